// Round 9
// baseline (2690.034 us; speedup 1.0000x reference)
//
#include <hip/hip_runtime.h>

// ---------------------------------------------------------------------------
// ERC GNN forward — round 12:
//  * BN stats FUSED into agg epilogues with 64-SLOT replication:
//    195 contributors/address at 2.8/µs arrival < ~4.8/µs same-address
//    f32 atomic service (r6/r7 measured) -> no queueing tail.
//    Slot region (1.18MB) aliases dead cnt/fill; k_collapse (1 blk)
//    precomputes mu/rs for classifier ids; fold_w reads slots directly.
//  * Self-GEMM stats epilogue slot-replicated (64), GAT GEMMs merged,
//    init folded into first classifier (r11).
//  * Aggs: 1 node/wave, pattern-roofline (r9/r10 nulls).
// ---------------------------------------------------------------------------

constexpr int D     = 256;
constexpr int NHEAD = 8;
constexpr int NCLS  = 7;
constexpr int NSLOT = 64;                   // stats slot replication
constexpr float BN_EPS = 1e-9f;

typedef short  s16x8 __attribute__((ext_vector_type(8)));
typedef float  f32x4 __attribute__((ext_vector_type(4)));

__device__ __forceinline__ unsigned short f2bf(float f) {
  unsigned int u = __builtin_bit_cast(unsigned int, f);
  u += 0x7FFFu + ((u >> 16) & 1u);          // round-to-nearest-even
  return (unsigned short)(u >> 16);
}
__device__ __forceinline__ float bf2f(unsigned short h) {
  unsigned int u = ((unsigned int)h) << 16;
  return __builtin_bit_cast(float, u);
}

__device__ __forceinline__ void gload_lds16(const void* g, void* l) {
  __builtin_amdgcn_global_load_lds(
      (const __attribute__((address_space(1))) unsigned int*)g,
      (__attribute__((address_space(3))) unsigned int*)l, 16, 0, 0);
}

// ---------------- bf16 MFMA GEMM: C[M,cols] = A[M,256] @ Wt^T + bias --------
// Merged-GAT mode (attS!=null, grid.y=4 over 512 cols):
//   cols [0,256): att epilogue only; cols [256,512): relu path, bias=biasB.
// Normal mode: optional slot-replicated BN stats epilogue (bnOut).
__launch_bounds__(256)
__global__ void k_gemm_mfma(const unsigned short* __restrict__ A,
                            const unsigned short* __restrict__ Wt,
                            const float* __restrict__ bias,
                            const float* __restrict__ biasB,
                            unsigned short* __restrict__ C,
                            int M, int doRelu,
                            const float* __restrict__ a_s, const float* __restrict__ a_n,
                            float* __restrict__ attS, float* __restrict__ attN,
                            float* __restrict__ bnOut)
{
  __shared__ unsigned short As[128 * 32];
  __shared__ unsigned short Bs[128 * 32];
  const int t = threadIdx.x;
  const int wave = t >> 6, lane = t & 63;
  const int quad = lane >> 4, l16 = lane & 15;
  const int wm = (wave & 1) * 64, wn = (wave >> 1) * 64;
  const int bm = blockIdx.x * 128, bn = blockIdx.y * 128;

  f32x4 acc[4][4] = {};

  const int rA0 = wave * 32 + (lane >> 2);
  const int rA1 = rA0 + 16;
  const int sub = (lane & 3) * 8;
  const unsigned short* gA0 = A  + (size_t)min(bm + rA0, M - 1) * D + sub;
  const unsigned short* gA1 = A  + (size_t)min(bm + rA1, M - 1) * D + sub;
  const unsigned short* gB0 = Wt + (size_t)(bn + rA0) * D + sub;
  const unsigned short* gB1 = Wt + (size_t)(bn + rA1) * D + sub;
  unsigned short* lA0 = &As[wave * 1024];
  unsigned short* lA1 = &As[wave * 1024 + 512];
  unsigned short* lB0 = &Bs[wave * 1024];
  unsigned short* lB1 = &Bs[wave * 1024 + 512];

  for (int k0 = 0; k0 < D; k0 += 32) {
    gload_lds16(gA0 + k0, lA0);
    gload_lds16(gA1 + k0, lA1);
    gload_lds16(gB0 + k0, lB0);
    gload_lds16(gB1 + k0, lB1);
    __syncthreads();
    s16x8 af[4], bf[4];
#pragma unroll
    for (int mi = 0; mi < 4; ++mi)
      af[mi] = *(const s16x8*)(&As[(wm + mi * 16 + l16) * 32 + quad * 8]);
#pragma unroll
    for (int nj = 0; nj < 4; ++nj)
      bf[nj] = *(const s16x8*)(&Bs[(wn + nj * 16 + l16) * 32 + quad * 8]);
#pragma unroll
    for (int mi = 0; mi < 4; ++mi)
#pragma unroll
      for (int nj = 0; nj < 4; ++nj)
        acc[mi][nj] = __builtin_amdgcn_mfma_f32_16x16x32_bf16(af[mi], bf[nj], acc[mi][nj], 0, 0, 0);
    __syncthreads();
  }

  // C/D layout: col = l16, row = quad*4 + reg (m89-verified)
  const bool attSlab = (attS != nullptr) && (bn < 256);
  if (attSlab) {
    const int hb = (bn + wn) >> 5;
#pragma unroll
    for (int mi = 0; mi < 4; ++mi) {
#pragma unroll
      for (int h = 0; h < 2; ++h) {
        float ps[4] = {}, pn[4] = {};
#pragma unroll
        for (int j = 0; j < 2; ++j) {
          const int nj = h * 2 + j;
          const int col = bn + wn + nj * 16 + l16;
          const float bv = bias[col];
          const float av = a_s[col], nv = a_n[col];
#pragma unroll
          for (int r = 0; r < 4; ++r) {
            const float v = fmaxf(acc[mi][nj][r] + bv, 0.f);
            ps[r] = fmaf(v, av, ps[r]);
            pn[r] = fmaf(v, nv, pn[r]);
          }
        }
#pragma unroll
        for (int m = 1; m < 16; m <<= 1)
#pragma unroll
          for (int r = 0; r < 4; ++r) {
            ps[r] += __shfl_xor(ps[r], m);
            pn[r] += __shfl_xor(pn[r], m);
          }
        if (l16 == 0) {
#pragma unroll
          for (int r = 0; r < 4; ++r) {
            const int row = bm + wm + mi * 16 + quad * 4 + r;
            if (row < M) {
              const float s_ = ps[r], n_ = pn[r];
              attS[(size_t)row * NHEAD + hb + h] = (s_ > 0.f) ? s_ : 0.2f * s_;
              attN[(size_t)row * NHEAD + hb + h] = (n_ > 0.f) ? n_ : 0.2f * n_;
            }
          }
        }
      }
    }
  } else {
    // normal path; in merged-GAT mode this is the Wn slab (cols 256..511)
    const int cBase = (attS != nullptr) ? 256 : 0;
    const float* bsrc = (attS != nullptr) ? biasB : bias;
    float cs[4] = {}, cq[4] = {};
#pragma unroll
    for (int nj = 0; nj < 4; ++nj) {
      const int col = bn + wn + nj * 16 + l16;       // Wt row index
      const int cw  = col - cBase;                   // output col
      const float bv = bsrc[cw];
#pragma unroll
      for (int mi = 0; mi < 4; ++mi) {
#pragma unroll
        for (int r = 0; r < 4; ++r) {
          const int row = bm + wm + mi * 16 + quad * 4 + r;
          if (row < M) {
            float v = acc[mi][nj][r] + bv;
            if (doRelu) v = fmaxf(v, 0.f);
            const unsigned short u = f2bf(v);
            C[(size_t)row * D + cw] = u;
            if (bnOut) {
              const float w = bf2f(u);
              cs[nj] += w;
              cq[nj] = fmaf(w, w, cq[nj]);
            }
          }
        }
      }
    }
    if (bnOut) {
#pragma unroll
      for (int nj = 0; nj < 4; ++nj) {
        cs[nj] += __shfl_xor(cs[nj], 16);
        cq[nj] += __shfl_xor(cq[nj], 16);
        cs[nj] += __shfl_xor(cs[nj], 32);
        cq[nj] += __shfl_xor(cq[nj], 32);
      }
      if (quad == 0) {
        float* slot = bnOut + (size_t)(blockIdx.x & (NSLOT - 1)) * 2 * D;
#pragma unroll
        for (int nj = 0; nj < 4; ++nj) {
          const int col = bn + wn + nj * 16 + l16;
          atomicAdd(&slot[col], cs[nj]);
          atomicAdd(&slot[D + col], cq[nj]);
        }
      }
    }
  }
}

// ---------------- conversions -----------------------------------------------
__global__ void k_cvt(const float* __restrict__ src, unsigned short* __restrict__ dst, int n8)
{
  const int i = blockIdx.x * 256 + threadIdx.x;
  if (i >= n8) return;
  const float4 a = *(const float4*)(src + (size_t)i * 8);
  const float4 b = *(const float4*)(src + (size_t)i * 8 + 4);
  uint4 o;
  o.x = (unsigned)f2bf(a.x) | ((unsigned)f2bf(a.y) << 16);
  o.y = (unsigned)f2bf(a.z) | ((unsigned)f2bf(a.w) << 16);
  o.z = (unsigned)f2bf(b.x) | ((unsigned)f2bf(b.y) << 16);
  o.w = (unsigned)f2bf(b.z) | ((unsigned)f2bf(b.w) << 16);
  *(uint4*)(dst + (size_t)i * 8) = o;
}

__global__ void k_cvt_w(const float* __restrict__ gat_Ws, const float* __restrict__ gat_Wn,
                        const float* __restrict__ gcn_W, const float* __restrict__ self_W,
                        unsigned short* __restrict__ Wt)
{
  const int m = blockIdx.x >> 8, j = blockIdx.x & 255, d = threadIdx.x;
  float v;
  if (m < 4) {
    const int l = m >> 1;
    const float* W = (m & 1) ? gat_Wn : gat_Ws;          // [L,H,D,DH]
    v = W[(((size_t)l * NHEAD + (j >> 5)) * D + d) * 32 + (j & 31)];
  } else if (m < 10) {
    v = gcn_W[((size_t)(m - 4) * D + d) * D + j];         // [3*L,D,D]
  } else {
    v = self_W[(size_t)d * D + j];
  }
  Wt[((size_t)m * D + j) * D + d] = f2bf(v);
}

// ---------------- BN-fold: W'[j,d] = rs_d*W[j,d]; b'[j] = b[j]-Σ mu_d*W'[j,d]
// sums = 64-slot base. mode 0: GAT layout [H,D,DH]; mode 1: GCN [D_in,D_out]
__global__ void k_fold_w(const float* __restrict__ srcW, const float* __restrict__ srcB,
                         const float* __restrict__ sums, unsigned short* __restrict__ dstW,
                         float* __restrict__ dstB, int mode, int Nn)
{
  __shared__ float red[256];
  const int j = blockIdx.x;      // out col
  const int d = threadIdx.x;     // in dim (BN axis)
  float sAcc = 0.f, qAcc = 0.f;
  for (int s8 = 0; s8 < NSLOT; ++s8) {
    sAcc += sums[(size_t)s8 * 2 * D + d];
    qAcc += sums[(size_t)s8 * 2 * D + D + d];
  }
  const float inv = 1.f / (float)Nn;
  const float m_ = sAcc * inv;
  const float rs = rsqrtf(qAcc * inv - m_ * m_ + BN_EPS);
  float w;
  if (mode == 0) w = srcW[(((size_t)(j >> 5)) * D + d) * 32 + (j & 31)];
  else           w = srcW[(size_t)d * D + j];
  const unsigned short q = f2bf(w * rs);
  dstW[(size_t)j * D + d] = q;
  red[d] = m_ * bf2f(q);         // use quantized weight so fold is exact vs GEMM
  __syncthreads();
  for (int off = 128; off > 0; off >>= 1) {
    if (d < off) red[d] += red[d + off];
    __syncthreads();
  }
  if (d == 0) dstB[j] = srcB[j] - red[0];
}

// ---------------- collapse 64-slot sums -> mu[256] | rs[256] ----------------
__global__ void k_collapse(const float* __restrict__ sums, float* __restrict__ murs, int Nn)
{
  const int t = threadIdx.x;     // 256
  float sAcc = 0.f, qAcc = 0.f;
  for (int s8 = 0; s8 < NSLOT; ++s8) {
    sAcc += sums[(size_t)s8 * 2 * D + t];
    qAcc += sums[(size_t)s8 * 2 * D + D + t];
  }
  const float inv = 1.f / (float)Nn;
  const float m_ = sAcc * inv;
  murs[t]     = m_;
  murs[D + t] = rsqrtf(qAcc * inv - m_ * m_ + BN_EPS);
}

// ---------------- batched CSR build (4 adjacencies) --------------------------
__global__ void k_count(const int* __restrict__ rows, int* __restrict__ cnt, int E4, int E, int N)
{
  const int i = blockIdx.x * 256 + threadIdx.x;
  if (i < E4) atomicAdd(&cnt[(i / E) * N + rows[i]], 1);
}

__global__ void k_scan_blk(const int* __restrict__ in, int* __restrict__ scanTmp,
                           int* __restrict__ blkSum, int n)
{
  __shared__ int buf[256];
  const int t = threadIdx.x, i = blockIdx.x * 256 + t;
  const int v = (i < n) ? in[i] : 0;
  buf[t] = v; __syncthreads();
  for (int off = 1; off < 256; off <<= 1) {
    const int x = (t >= off) ? buf[t - off] : 0;
    __syncthreads();
    buf[t] += x; __syncthreads();
  }
  if (i < n) scanTmp[i] = buf[t];
  if (t == 255) blkSum[blockIdx.x] = buf[255];
}

__global__ void k_scan_top(int* __restrict__ blkSum, int G)
{
  __shared__ int buf[1024];
  const int t = threadIdx.x;
  const int v = (t < G) ? blkSum[t] : 0;
  buf[t] = v; __syncthreads();
  for (int off = 1; off < 1024; off <<= 1) {
    const int x = (t >= off) ? buf[t - off] : 0;
    __syncthreads();
    buf[t] += x; __syncthreads();
  }
  if (t < G) blkSum[t] = buf[t] - v;
}

__global__ void k_scan_fin(const int* __restrict__ scanTmp, const int* __restrict__ blkOff,
                           int* __restrict__ rowptr, int n)
{
  const int i = blockIdx.x * 256 + threadIdx.x;
  if (i < n) rowptr[i + 1] = scanTmp[i] + blkOff[blockIdx.x];
  if (i == 0) rowptr[0] = 0;
}

// packed scatter: one 8B store per edge {col, val-bits}
__global__ void k_scatter(const int* __restrict__ rows, const int* __restrict__ cols,
                          const float* __restrict__ vals,
                          const int* __restrict__ rowptr, int* __restrict__ fill,
                          int2* __restrict__ edge, int E4, int E, int N)
{
  const int i = blockIdx.x * 256 + threadIdx.x;
  if (i >= E4) return;
  const int g = (i / E) * N + rows[i];
  const int p = rowptr[g] + atomicAdd(&fill[g], 1);
  edge[p] = make_int2(cols[i], __float_as_int(vals[i]));
}

// ---------------- Aggregations: 1 node/WAVE + fused 64-slot BN stats --------
__device__ __forceinline__ void acc8(float* a, uint4 f, float c) {
  const unsigned w[4] = {f.x, f.y, f.z, f.w};
#pragma unroll
  for (int k = 0; k < 4; ++k) {
    a[2 * k]     = fmaf(c, bf2f((unsigned short)(w[k] & 0xffff)), a[2 * k]);
    a[2 * k + 1] = fmaf(c, bf2f((unsigned short)(w[k] >> 16)),    a[2 * k + 1]);
  }
}

// block stats reduce: half-0 lanes of 4 waves hold s/q for cols c32*8+k
__device__ __forceinline__ void stats_reduce64(const float* s, const float* q,
                                               float* __restrict__ sums)
{
  __shared__ float ls[128][8];
  __shared__ float lq[128][8];
  const int t = threadIdx.x;
  const int c32 = t & 31;
  if ((t & 32) == 0) {
    const int idx = ((t >> 6) << 5) | c32;   // 0..127
#pragma unroll
    for (int k = 0; k < 8; ++k) { ls[idx][k] = s[k]; lq[idx][k] = q[k]; }
  }
  __syncthreads();
  if (t < 32) {
    float* slot = sums + (size_t)(blockIdx.x & (NSLOT - 1)) * 2 * D;
#pragma unroll
    for (int k = 0; k < 8; ++k) {
      const float ss = ls[t][k] + ls[t + 32][k] + ls[t + 64][k] + ls[t + 96][k];
      const float qq = lq[t][k] + lq[t + 32][k] + lq[t + 64][k] + lq[t + 96][k];
      atomicAdd(&slot[t * 8 + k], ss);
      atomicAdd(&slot[D + t * 8 + k], qq);
    }
  }
}

__global__ void k_gat_agg(const unsigned short* __restrict__ fneigh,
                          const float* __restrict__ attS, const float* __restrict__ attN,
                          const int* __restrict__ rowptr, const int2* __restrict__ edge,
                          unsigned short* __restrict__ out, float* __restrict__ sums, int N)
{
  const int n = blockIdx.x * 4 + (threadIdx.x >> 6);
  const int lane = threadIdx.x & 63;
  const int half = lane >> 5;                 // which edge of the pair
  const int c32  = lane & 31;                 // 8 cols/lane
  const int head = c32 >> 2;                  // 32 cols/head
  float s[8] = {}, q[8] = {};
  if (n < N) {                                // wave-uniform, no early return
    const float as = attS[(size_t)n * NHEAD + head];
    float a[8] = {};
    int p = rowptr[n];
    const int e = rowptr[n + 1];
    for (; p + 3 < e; p += 4) {               // 4 edges / iter (2 pairs)
      const int2 ea = edge[p + half];
      const int2 eb = edge[p + 2 + half];
      const float ca = (as + attN[(size_t)ea.x * NHEAD + head]) * __int_as_float(ea.y);
      const float cb = (as + attN[(size_t)eb.x * NHEAD + head]) * __int_as_float(eb.y);
      const uint4 fa = *(const uint4*)(fneigh + (size_t)ea.x * D + c32 * 8);
      const uint4 fb = *(const uint4*)(fneigh + (size_t)eb.x * D + c32 * 8);
      acc8(a, fa, ca);
      acc8(a, fb, cb);
    }
    if (p + 1 < e) {                          // one full pair
      const int2 ea = edge[p + half];
      const float ca = (as + attN[(size_t)ea.x * NHEAD + head]) * __int_as_float(ea.y);
      const uint4 fa = *(const uint4*)(fneigh + (size_t)ea.x * D + c32 * 8);
      acc8(a, fa, ca);
      p += 2;
    }
    if (p < e && half == 0) {                 // last single edge: lower half
      const int2 ea = edge[p];
      const float ca = (as + attN[(size_t)ea.x * NHEAD + head]) * __int_as_float(ea.y);
      const uint4 fa = *(const uint4*)(fneigh + (size_t)ea.x * D + c32 * 8);
      acc8(a, fa, ca);
    }
#pragma unroll
    for (int k = 0; k < 8; ++k) a[k] += __shfl_xor(a[k], 32);
    if (half == 0) {
      unsigned ov[4];
#pragma unroll
      for (int k = 0; k < 4; ++k) {
        const unsigned short ulo = f2bf(a[2 * k]), uhi = f2bf(a[2 * k + 1]);
        ov[k] = (unsigned)ulo | ((unsigned)uhi << 16);
        const float lo = bf2f(ulo), hi = bf2f(uhi);
        s[2 * k]     = lo; q[2 * k]     = lo * lo;
        s[2 * k + 1] = hi; q[2 * k + 1] = hi * hi;
      }
      uint4 o; o.x = ov[0]; o.y = ov[1]; o.z = ov[2]; o.w = ov[3];
      *(uint4*)(out + (size_t)n * D + c32 * 8) = o;
    }
  }
  stats_reduce64(s, q, sums);
}

__global__ void k_gcn_agg(const unsigned short* __restrict__ Hm,
                          const int* __restrict__ rowptr, const int2* __restrict__ edge,
                          unsigned short* __restrict__ out, float* __restrict__ sums, int N)
{
  const int n = blockIdx.x * 4 + (threadIdx.x >> 6);
  const int lane = threadIdx.x & 63;
  const int half = lane >> 5;
  const int c32  = lane & 31;
  float s[8] = {}, q[8] = {};
  if (n < N) {                                // wave-uniform, no early return
    float a[8] = {};
    int p = rowptr[n];
    const int e = rowptr[n + 1];
    for (; p + 3 < e; p += 4) {               // 4 edges / iter (2 pairs)
      const int2 ea = edge[p + half];
      const int2 eb = edge[p + 2 + half];
      const uint4 fa = *(const uint4*)(Hm + (size_t)ea.x * D + c32 * 8);
      const uint4 fb = *(const uint4*)(Hm + (size_t)eb.x * D + c32 * 8);
      acc8(a, fa, __int_as_float(ea.y));
      acc8(a, fb, __int_as_float(eb.y));
    }
    if (p + 1 < e) {                          // one full pair
      const int2 ea = edge[p + half];
      const uint4 fa = *(const uint4*)(Hm + (size_t)ea.x * D + c32 * 8);
      acc8(a, fa, __int_as_float(ea.y));
      p += 2;
    }
    if (p < e && half == 0) {                 // last single edge: lower half
      const int2 ea = edge[p];
      const uint4 fa = *(const uint4*)(Hm + (size_t)ea.x * D + c32 * 8);
      acc8(a, fa, __int_as_float(ea.y));
    }
#pragma unroll
    for (int k = 0; k < 8; ++k) a[k] += __shfl_xor(a[k], 32);
    if (half == 0) {
      unsigned ov[4];
#pragma unroll
      for (int k = 0; k < 4; ++k) {
        const float vlo = fmaxf(a[2 * k], 0.f), vhi = fmaxf(a[2 * k + 1], 0.f); // relu pre-BN
        const unsigned short ulo = f2bf(vlo), uhi = f2bf(vhi);
        ov[k] = (unsigned)ulo | ((unsigned)uhi << 16);
        const float lo = bf2f(ulo), hi = bf2f(uhi);
        s[2 * k]     = lo; q[2 * k]     = lo * lo;
        s[2 * k + 1] = hi; q[2 * k + 1] = hi * hi;
      }
      uint4 o; o.x = ov[0]; o.y = ov[1]; o.z = ov[2]; o.w = ov[3];
      *(uint4*)(out + (size_t)n * D + c32 * 8) = o;
    }
  }
  stats_reduce64(s, q, sums);
}

// ---------------- Classifier (BN folded in; murs = mu[256]|rs[256]) ---------
__global__ void k_classifier(const unsigned short* __restrict__ F, const float* __restrict__ W,
                             const float* __restrict__ murs, const float* __restrict__ cls_b,
                             float* __restrict__ out, int N, int baseRow, int initMode)
{
  __shared__ float smu[D], srs[D];
  const int t = threadIdx.x;
  smu[t] = murs[t];
  srs[t] = murs[D + t];
  __syncthreads();

  const int n = blockIdx.x * 8 + (t >> 5);
  if (n >= N) return;
  const int lane = t & 31;
  const uint4 f = *(const uint4*)(F + (size_t)n * D + lane * 8);
  const unsigned w[4] = {f.x, f.y, f.z, f.w};
  float fv[8];
#pragma unroll
  for (int k = 0; k < 4; ++k) {
    fv[2 * k]     = (bf2f((unsigned short)(w[k] & 0xffff)) - smu[lane * 8 + 2 * k])     * srs[lane * 8 + 2 * k];
    fv[2 * k + 1] = (bf2f((unsigned short)(w[k] >> 16))    - smu[lane * 8 + 2 * k + 1]) * srs[lane * 8 + 2 * k + 1];
  }
  const float* Wr = W + (size_t)(baseRow + lane * 8) * NCLS;
  float p[NCLS];
#pragma unroll
  for (int c = 0; c < NCLS; ++c) {
    float s = 0.f;
#pragma unroll
    for (int k = 0; k < 8; ++k) s = fmaf(fv[k], Wr[k * NCLS + c], s);
    p[c] = s;
  }
#pragma unroll
  for (int m = 1; m < 32; m <<= 1)
#pragma unroll
    for (int c = 0; c < NCLS; ++c) p[c] += __shfl_xor(p[c], m);
  if (lane == 0) {
    float* o = out + (size_t)n * NCLS;
    if (initMode) {
#pragma unroll
      for (int c = 0; c < NCLS; ++c) o[c] = p[c] + cls_b[c];
    } else {
#pragma unroll
      for (int c = 0; c < NCLS; ++c) o[c] += p[c];
    }
  }
}

// ---------------------------------------------------------------------------
extern "C" void kernel_launch(void* const* d_in, const int* in_sizes, int n_in,
                              void* d_out, int out_size, void* d_ws, size_t ws_size,
                              hipStream_t stream)
{
  const float* f_in   = (const float*)d_in[0];
  const int*   erow   = (const int*)d_in[1];
  const int*   ecol   = (const int*)d_in[2];
  const float* eval   = (const float*)d_in[3];
  const float* gat_Ws = (const float*)d_in[4];
  const float* gat_bs = (const float*)d_in[5];
  const float* gat_Wn = (const float*)d_in[6];
  const float* gat_bn = (const float*)d_in[7];
  const float* gat_as = (const float*)d_in[8];
  const float* gat_an = (const float*)d_in[9];
  const float* gcn_W  = (const float*)d_in[10];
  const float* gcn_b  = (const float*)d_in[11];
  const float* self_W = (const float*)d_in[12];
  const float* self_b = (const float*)d_in[13];
  const float* cls_W  = (const float*)d_in[14];
  const float* cls_b  = (const float*)d_in[15];
  float* out = (float*)d_out;

  const int N  = in_sizes[0] / D;      // 50000
  const int E  = in_sizes[1] / 4;      // 400000
  const int E4 = 4 * E, N4 = 4 * N;
  const size_t ND = (size_t)N * D;

  // ---- workspace carve-up (byte-identical footprint to round 3) ----
  unsigned short* bufA = (unsigned short*)d_ws;
  unsigned short* bufB = bufA + ND;
  unsigned short* bufC = bufB + ND;
  unsigned short* finB = bufC + ND;
  unsigned short* Wt   = finB + ND;                 // 11*65536
  float* attS   = (float*)(Wt + (size_t)11 * D * D);
  float* attN   = attS + (size_t)N * NHEAD;
  int*   scanTmp= (int*)(attN + (size_t)N * NHEAD);
  int*   blkSum = scanTmp + N4;
  int*   rowptr = blkSum + 1024;
  int2*  edge   = (int2*)(rowptr + (N4 + 4));
  // zeroed region: cnt[4N] | fill[4N]
  int*   cnt    = (int*)(edge + E4);
  int*   fill   = cnt + N4;
  // foldB + murs alias scanTmp (dead after CSR build)
  float* foldB    = (float*)scanTmp;               // 5*256 floats
  float* murs     = (float*)scanTmp + 2048;        // 9*512 floats
  // 64-slot stats sums alias cnt/fill (dead after k_scatter):
  // 9 ids * 64 slots * 2*D floats = 1.18 MB <= 1.6 MB
  float* slotSums = (float*)cnt;
  const size_t zero_bytes = (size_t)(2 * N4) * sizeof(int);
  const size_t slot_bytes = (size_t)9 * NSLOT * 2 * D * sizeof(float);

  const dim3 gemm_grid((N + 127) / 128, D / 128);
  const dim3 gemm_grid2((N + 127) / 128, 4);    // merged GAT: 512 cols
  const int nb8   = (N + 7) / 8;
  const int nb4   = (N + 3) / 4;       // agg: 1 node/wave, 4 waves/block
  const int scanG = (N4 + 255) / 256;

  hipMemsetAsync(cnt, 0, zero_bytes, stream);

  // conversions
  k_cvt  <<<(int)(ND / 8 + 255) / 256, 256, 0, stream>>>(f_in, finB, (int)(ND / 8));
  k_cvt_w<<<11 * 256, 256, 0, stream>>>(gat_Ws, gat_Wn, gcn_W, self_W, Wt);

  // batched CSR for 4 adjacencies
  k_count   <<<(E4 + 255) / 256, 256, 0, stream>>>(erow, cnt, E4, E, N);
  k_scan_blk<<<scanG, 256, 0, stream>>>(cnt, scanTmp, blkSum, N4);
  k_scan_top<<<1, 1024, 0, stream>>>(blkSum, scanG);
  k_scan_fin<<<scanG, 256, 0, stream>>>(scanTmp, blkSum, rowptr, N4);
  k_scatter <<<(E4 + 255) / 256, 256, 0, stream>>>(erow, ecol, eval, rowptr, fill,
                                                   edge, E4, E, N);

  // cnt/fill and scanTmp are dead now — zero the aliased slot-sums region
  hipMemsetAsync(slotSums, 0, slot_bytes, stream);

  const size_t WM = (size_t)D * D;
  auto sumsOf = [&](int id) { return slotSums + (size_t)id * NSLOT * 2 * D; };
  auto mursOf = [&](int id) { return murs + (size_t)id * 2 * D; };

  // ===================== GAT branch (adjacency 0) ==========================
  {
    const int* rp = rowptr;
    // layer 0: MERGED GEMM — slab0 = Ws(att only), slab1 = Wn -> bufB
    k_gemm_mfma<<<gemm_grid2, 256, 0, stream>>>(finB, Wt + 0 * WM, gat_bs, gat_bn,
                                                bufB, N, 1,
                                                gat_as, gat_an, attS, attN, nullptr);
    k_gat_agg  <<<nb4, 256, 0, stream>>>(bufB, attS, attN, rp, edge, bufC,
                                         sumsOf(0), N);
    // fold BN(0) into layer-1 weights (both Ws and Wn consume bufC)
    k_fold_w<<<D, 256, 0, stream>>>(gat_Ws + (size_t)NHEAD * D * 32, gat_bs + D,
                                    sumsOf(0), Wt + 2 * WM, foldB + 0 * D, 0, N);
    k_fold_w<<<D, 256, 0, stream>>>(gat_Wn + (size_t)NHEAD * D * 32, gat_bn + D,
                                    sumsOf(0), Wt + 3 * WM, foldB + 1 * D, 0, N);
    // layer 1: MERGED GEMM — slab0 = Ws'(att only), slab1 = Wn' -> bufB
    k_gemm_mfma<<<gemm_grid2, 256, 0, stream>>>(bufC, Wt + 2 * WM, foldB + 0 * D,
                                                foldB + 1 * D, bufB, N, 1,
                                                gat_as + D, gat_an + D, attS, attN, nullptr);
    k_gat_agg  <<<nb4, 256, 0, stream>>>(bufB, attS, attN, rp, edge, bufA,
                                         sumsOf(1), N);
    k_collapse<<<1, 256, 0, stream>>>(sumsOf(1), mursOf(1), N);
    k_classifier<<<nb8, 256, 0, stream>>>(bufA, cls_W, mursOf(1), cls_b, out, N, 0, 1);
  }

  // ===================== 3 GCN branches (adjacency 1..3) ===================
  for (int g = 0; g < 3; ++g) {
    const int* rp = rowptr + (size_t)(g + 1) * N;
    const float* bg = gcn_b + (size_t)g * 2 * D;
    k_gemm_mfma<<<gemm_grid, 256, 0, stream>>>(finB, Wt + (4 + 2 * g) * WM, bg, bg,
                                               bufA, N, 0,
                                               nullptr, nullptr, nullptr, nullptr, nullptr);
    k_gcn_agg  <<<nb4, 256, 0, stream>>>(bufA, rp, edge, bufB, sumsOf(2 + 2 * g), N);
    // fold BN(2+2g) into layer-2 weights
    k_fold_w<<<D, 256, 0, stream>>>(gcn_W + (size_t)(2 * g + 1) * D * D, bg + D,
                                    sumsOf(2 + 2 * g),
                                    Wt + (5 + 2 * g) * WM, foldB + (2 + g) * D, 1, N);
    k_gemm_mfma<<<gemm_grid, 256, 0, stream>>>(bufB, Wt + (5 + 2 * g) * WM,
                                               foldB + (2 + g) * D, foldB + (2 + g) * D,
                                               bufA, N, 0,
                                               nullptr, nullptr, nullptr, nullptr, nullptr);
    k_gcn_agg  <<<nb4, 256, 0, stream>>>(bufA, rp, edge, bufB, sumsOf(3 + 2 * g), N);
    k_collapse<<<1, 256, 0, stream>>>(sumsOf(3 + 2 * g), mursOf(3 + 2 * g), N);
    k_classifier<<<nb8, 256, 0, stream>>>(bufB, cls_W, mursOf(3 + 2 * g), cls_b,
                                          out, N, (1 + g) * D, 0);
  }

  // ===================== self perceptron (stats fused, 64-slot) ============
  k_gemm_mfma<<<gemm_grid, 256, 0, stream>>>(finB, Wt + 10 * WM, self_b, self_b,
                                             bufA, N, 1,
                                             nullptr, nullptr, nullptr, nullptr,
                                             sumsOf(8));
  k_collapse<<<1, 256, 0, stream>>>(sumsOf(8), mursOf(8), N);
  k_classifier<<<nb8, 256, 0, stream>>>(bufA, cls_W, mursOf(8), cls_b, out, N, 4 * D, 0);
}

// Round 11
// 1254.783 us; speedup vs baseline: 2.1438x; 2.1438x over previous
//
#include <hip/hip_runtime.h>

// ---------------------------------------------------------------------------
// ERC GNN forward — round 14 (round-13 resubmit; r10 bench failure was infra,
// same signature as round 1 which passed on resubmit; source audited clean):
//  * LESSON (r12): fused stats = 6.4M atomics/dispatch -> 175MB RMW traffic.
//    Atomics cost per-op L2-RMW bandwidth, not just same-address serialization.
//    Aggs in r11 form (no stats epilogue).
//  * k_bn_stats: 1024 blocks (4x read concurrency) + 64-slot sums;
//    k_collapse precomputes mu/rs; fold_w reads 64 slots directly.
//  * k_cvt_w: LDS 32x32 tile transpose (was stride-1KB reads, ~45MB ampl).
//  * r11 kept: merged GAT GEMMs, fused self-GEMM stats, init-folded classifier.
// ---------------------------------------------------------------------------

constexpr int D     = 256;
constexpr int NHEAD = 8;
constexpr int NCLS  = 7;
constexpr int NSLOT = 64;                   // stats slot replication
constexpr float BN_EPS = 1e-9f;

typedef short  s16x8 __attribute__((ext_vector_type(8)));
typedef float  f32x4 __attribute__((ext_vector_type(4)));

__device__ __forceinline__ unsigned short f2bf(float f) {
  unsigned int u = __builtin_bit_cast(unsigned int, f);
  u += 0x7FFFu + ((u >> 16) & 1u);          // round-to-nearest-even
  return (unsigned short)(u >> 16);
}
__device__ __forceinline__ float bf2f(unsigned short h) {
  unsigned int u = ((unsigned int)h) << 16;
  return __builtin_bit_cast(float, u);
}

__device__ __forceinline__ void gload_lds16(const void* g, void* l) {
  __builtin_amdgcn_global_load_lds(
      (const __attribute__((address_space(1))) unsigned int*)g,
      (__attribute__((address_space(3))) unsigned int*)l, 16, 0, 0);
}

// ---------------- bf16 MFMA GEMM: C[M,cols] = A[M,256] @ Wt^T + bias --------
// Merged-GAT mode (attS!=null, grid.y=4 over 512 cols):
//   cols [0,256): att epilogue only; cols [256,512): relu path, bias=biasB.
// Normal mode: optional slot-replicated BN stats epilogue (bnOut).
__launch_bounds__(256)
__global__ void k_gemm_mfma(const unsigned short* __restrict__ A,
                            const unsigned short* __restrict__ Wt,
                            const float* __restrict__ bias,
                            const float* __restrict__ biasB,
                            unsigned short* __restrict__ C,
                            int M, int doRelu,
                            const float* __restrict__ a_s, const float* __restrict__ a_n,
                            float* __restrict__ attS, float* __restrict__ attN,
                            float* __restrict__ bnOut)
{
  __shared__ unsigned short As[128 * 32];
  __shared__ unsigned short Bs[128 * 32];
  const int t = threadIdx.x;
  const int wave = t >> 6, lane = t & 63;
  const int quad = lane >> 4, l16 = lane & 15;
  const int wm = (wave & 1) * 64, wn = (wave >> 1) * 64;
  const int bm = blockIdx.x * 128, bn = blockIdx.y * 128;

  f32x4 acc[4][4] = {};

  const int rA0 = wave * 32 + (lane >> 2);
  const int rA1 = rA0 + 16;
  const int sub = (lane & 3) * 8;
  const unsigned short* gA0 = A  + (size_t)min(bm + rA0, M - 1) * D + sub;
  const unsigned short* gA1 = A  + (size_t)min(bm + rA1, M - 1) * D + sub;
  const unsigned short* gB0 = Wt + (size_t)(bn + rA0) * D + sub;
  const unsigned short* gB1 = Wt + (size_t)(bn + rA1) * D + sub;
  unsigned short* lA0 = &As[wave * 1024];
  unsigned short* lA1 = &As[wave * 1024 + 512];
  unsigned short* lB0 = &Bs[wave * 1024];
  unsigned short* lB1 = &Bs[wave * 1024 + 512];

  for (int k0 = 0; k0 < D; k0 += 32) {
    gload_lds16(gA0 + k0, lA0);
    gload_lds16(gA1 + k0, lA1);
    gload_lds16(gB0 + k0, lB0);
    gload_lds16(gB1 + k0, lB1);
    __syncthreads();
    s16x8 af[4], bf[4];
#pragma unroll
    for (int mi = 0; mi < 4; ++mi)
      af[mi] = *(const s16x8*)(&As[(wm + mi * 16 + l16) * 32 + quad * 8]);
#pragma unroll
    for (int nj = 0; nj < 4; ++nj)
      bf[nj] = *(const s16x8*)(&Bs[(wn + nj * 16 + l16) * 32 + quad * 8]);
#pragma unroll
    for (int mi = 0; mi < 4; ++mi)
#pragma unroll
      for (int nj = 0; nj < 4; ++nj)
        acc[mi][nj] = __builtin_amdgcn_mfma_f32_16x16x32_bf16(af[mi], bf[nj], acc[mi][nj], 0, 0, 0);
    __syncthreads();
  }

  // C/D layout: col = l16, row = quad*4 + reg (m89-verified)
  const bool attSlab = (attS != nullptr) && (bn < 256);
  if (attSlab) {
    const int hb = (bn + wn) >> 5;
#pragma unroll
    for (int mi = 0; mi < 4; ++mi) {
#pragma unroll
      for (int h = 0; h < 2; ++h) {
        float ps[4] = {}, pn[4] = {};
#pragma unroll
        for (int j = 0; j < 2; ++j) {
          const int nj = h * 2 + j;
          const int col = bn + wn + nj * 16 + l16;
          const float bv = bias[col];
          const float av = a_s[col], nv = a_n[col];
#pragma unroll
          for (int r = 0; r < 4; ++r) {
            const float v = fmaxf(acc[mi][nj][r] + bv, 0.f);
            ps[r] = fmaf(v, av, ps[r]);
            pn[r] = fmaf(v, nv, pn[r]);
          }
        }
#pragma unroll
        for (int m = 1; m < 16; m <<= 1)
#pragma unroll
          for (int r = 0; r < 4; ++r) {
            ps[r] += __shfl_xor(ps[r], m);
            pn[r] += __shfl_xor(pn[r], m);
          }
        if (l16 == 0) {
#pragma unroll
          for (int r = 0; r < 4; ++r) {
            const int row = bm + wm + mi * 16 + quad * 4 + r;
            if (row < M) {
              const float s_ = ps[r], n_ = pn[r];
              attS[(size_t)row * NHEAD + hb + h] = (s_ > 0.f) ? s_ : 0.2f * s_;
              attN[(size_t)row * NHEAD + hb + h] = (n_ > 0.f) ? n_ : 0.2f * n_;
            }
          }
        }
      }
    }
  } else {
    // normal path; in merged-GAT mode this is the Wn slab (cols 256..511)
    const int cBase = (attS != nullptr) ? 256 : 0;
    const float* bsrc = (attS != nullptr) ? biasB : bias;
    float cs[4] = {}, cq[4] = {};
#pragma unroll
    for (int nj = 0; nj < 4; ++nj) {
      const int col = bn + wn + nj * 16 + l16;       // Wt row index
      const int cw  = col - cBase;                   // output col
      const float bv = bsrc[cw];
#pragma unroll
      for (int mi = 0; mi < 4; ++mi) {
#pragma unroll
        for (int r = 0; r < 4; ++r) {
          const int row = bm + wm + mi * 16 + quad * 4 + r;
          if (row < M) {
            float v = acc[mi][nj][r] + bv;
            if (doRelu) v = fmaxf(v, 0.f);
            const unsigned short u = f2bf(v);
            C[(size_t)row * D + cw] = u;
            if (bnOut) {
              const float w = bf2f(u);
              cs[nj] += w;
              cq[nj] = fmaf(w, w, cq[nj]);
            }
          }
        }
      }
    }
    if (bnOut) {
#pragma unroll
      for (int nj = 0; nj < 4; ++nj) {
        cs[nj] += __shfl_xor(cs[nj], 16);
        cq[nj] += __shfl_xor(cq[nj], 16);
        cs[nj] += __shfl_xor(cs[nj], 32);
        cq[nj] += __shfl_xor(cq[nj], 32);
      }
      if (quad == 0) {
        float* slot = bnOut + (size_t)(blockIdx.x & (NSLOT - 1)) * 2 * D;
#pragma unroll
        for (int nj = 0; nj < 4; ++nj) {
          const int col = bn + wn + nj * 16 + l16;
          atomicAdd(&slot[col], cs[nj]);
          atomicAdd(&slot[D + col], cq[nj]);
        }
      }
    }
  }
}

// ---------------- conversions -----------------------------------------------
__global__ void k_cvt(const float* __restrict__ src, unsigned short* __restrict__ dst, int n8)
{
  const int i = blockIdx.x * 256 + threadIdx.x;
  if (i >= n8) return;
  const float4 a = *(const float4*)(src + (size_t)i * 8);
  const float4 b = *(const float4*)(src + (size_t)i * 8 + 4);
  uint4 o;
  o.x = (unsigned)f2bf(a.x) | ((unsigned)f2bf(a.y) << 16);
  o.y = (unsigned)f2bf(a.z) | ((unsigned)f2bf(a.w) << 16);
  o.z = (unsigned)f2bf(b.x) | ((unsigned)f2bf(b.y) << 16);
  o.w = (unsigned)f2bf(b.z) | ((unsigned)f2bf(b.w) << 16);
  *(uint4*)(dst + (size_t)i * 8) = o;
}

// LDS tile-transposed weight conversion: reads and writes both coalesced.
// grid = (11 m-slabs, 8 j-tiles, 8 d-tiles), block = 256.
__global__ void k_cvt_w(const float* __restrict__ gat_Ws, const float* __restrict__ gat_Wn,
                        const float* __restrict__ gcn_W, const float* __restrict__ self_W,
                        unsigned short* __restrict__ Wt)
{
  __shared__ float tile[32][33];
  const int m = blockIdx.x, jt = blockIdx.y, dt = blockIdx.z;
  const int tx = threadIdx.x & 31, ty = threadIdx.x >> 5;
#pragma unroll
  for (int r = 0; r < 4; ++r) {
    const int dl = ty * 4 + r;                 // d_local
    const int d  = dt * 32 + dl;
    float v;
    if (m < 4) {
      const int l = m >> 1;
      const float* W = (m & 1) ? gat_Wn : gat_Ws;           // [L,H,D,DH]
      v = W[(((size_t)l * NHEAD + jt) * D + d) * 32 + tx];  // j>>5=jt, j&31=tx
    } else if (m < 10) {
      v = gcn_W[((size_t)(m - 4) * D + d) * D + jt * 32 + tx];
    } else {
      v = self_W[(size_t)d * D + jt * 32 + tx];
    }
    tile[dl][tx] = v;                          // [d_local][j_local]
  }
  __syncthreads();
#pragma unroll
  for (int r = 0; r < 4; ++r) {
    const int jl = ty * 4 + r;                 // j_local
    const int j  = jt * 32 + jl;
    const int d  = dt * 32 + tx;
    Wt[((size_t)m * D + j) * D + d] = f2bf(tile[tx][jl]);
  }
}

// ---------------- BN-fold: W'[j,d] = rs_d*W[j,d]; b'[j] = b[j]-Σ mu_d*W'[j,d]
// sums = 64-slot base. mode 0: GAT layout [H,D,DH]; mode 1: GCN [D_in,D_out]
__global__ void k_fold_w(const float* __restrict__ srcW, const float* __restrict__ srcB,
                         const float* __restrict__ sums, unsigned short* __restrict__ dstW,
                         float* __restrict__ dstB, int mode, int Nn)
{
  __shared__ float red[256];
  const int j = blockIdx.x;      // out col
  const int d = threadIdx.x;     // in dim (BN axis)
  float sAcc = 0.f, qAcc = 0.f;
  for (int s8 = 0; s8 < NSLOT; ++s8) {
    sAcc += sums[(size_t)s8 * 2 * D + d];
    qAcc += sums[(size_t)s8 * 2 * D + D + d];
  }
  const float inv = 1.f / (float)Nn;
  const float m_ = sAcc * inv;
  const float rs = rsqrtf(qAcc * inv - m_ * m_ + BN_EPS);
  float w;
  if (mode == 0) w = srcW[(((size_t)(j >> 5)) * D + d) * 32 + (j & 31)];
  else           w = srcW[(size_t)d * D + j];
  const unsigned short q = f2bf(w * rs);
  dstW[(size_t)j * D + d] = q;
  red[d] = m_ * bf2f(q);         // use quantized weight so fold is exact vs GEMM
  __syncthreads();
  for (int off = 128; off > 0; off >>= 1) {
    if (d < off) red[d] += red[d + off];
    __syncthreads();
  }
  if (d == 0) dstB[j] = srcB[j] - red[0];
}

// ---------------- collapse 64-slot sums -> mu[256] | rs[256] ----------------
__global__ void k_collapse(const float* __restrict__ sums, float* __restrict__ murs, int Nn)
{
  const int t = threadIdx.x;     // 256
  float sAcc = 0.f, qAcc = 0.f;
  for (int s8 = 0; s8 < NSLOT; ++s8) {
    sAcc += sums[(size_t)s8 * 2 * D + t];
    qAcc += sums[(size_t)s8 * 2 * D + D + t];
  }
  const float inv = 1.f / (float)Nn;
  const float m_ = sAcc * inv;
  murs[t]     = m_;
  murs[D + t] = rsqrtf(qAcc * inv - m_ * m_ + BN_EPS);
}

// ---------------- batched CSR build (4 adjacencies) --------------------------
__global__ void k_count(const int* __restrict__ rows, int* __restrict__ cnt, int E4, int E, int N)
{
  const int i = blockIdx.x * 256 + threadIdx.x;
  if (i < E4) atomicAdd(&cnt[(i / E) * N + rows[i]], 1);
}

__global__ void k_scan_blk(const int* __restrict__ in, int* __restrict__ scanTmp,
                           int* __restrict__ blkSum, int n)
{
  __shared__ int buf[256];
  const int t = threadIdx.x, i = blockIdx.x * 256 + t;
  const int v = (i < n) ? in[i] : 0;
  buf[t] = v; __syncthreads();
  for (int off = 1; off < 256; off <<= 1) {
    const int x = (t >= off) ? buf[t - off] : 0;
    __syncthreads();
    buf[t] += x; __syncthreads();
  }
  if (i < n) scanTmp[i] = buf[t];
  if (t == 255) blkSum[blockIdx.x] = buf[255];
}

__global__ void k_scan_top(int* __restrict__ blkSum, int G)
{
  __shared__ int buf[1024];
  const int t = threadIdx.x;
  const int v = (t < G) ? blkSum[t] : 0;
  buf[t] = v; __syncthreads();
  for (int off = 1; off < 1024; off <<= 1) {
    const int x = (t >= off) ? buf[t - off] : 0;
    __syncthreads();
    buf[t] += x; __syncthreads();
  }
  if (t < G) blkSum[t] = buf[t] - v;
}

__global__ void k_scan_fin(const int* __restrict__ scanTmp, const int* __restrict__ blkOff,
                           int* __restrict__ rowptr, int n)
{
  const int i = blockIdx.x * 256 + threadIdx.x;
  if (i < n) rowptr[i + 1] = scanTmp[i] + blkOff[blockIdx.x];
  if (i == 0) rowptr[0] = 0;
}

// packed scatter: one 8B store per edge {col, val-bits}
__global__ void k_scatter(const int* __restrict__ rows, const int* __restrict__ cols,
                          const float* __restrict__ vals,
                          const int* __restrict__ rowptr, int* __restrict__ fill,
                          int2* __restrict__ edge, int E4, int E, int N)
{
  const int i = blockIdx.x * 256 + threadIdx.x;
  if (i >= E4) return;
  const int g = (i / E) * N + rows[i];
  const int p = rowptr[g] + atomicAdd(&fill[g], 1);
  edge[p] = make_int2(cols[i], __float_as_int(vals[i]));
}

// ---------------- Aggregations: 1 node/WAVE, half-waves split edge pairs ----
__device__ __forceinline__ void acc8(float* a, uint4 f, float c) {
  const unsigned w[4] = {f.x, f.y, f.z, f.w};
#pragma unroll
  for (int k = 0; k < 4; ++k) {
    a[2 * k]     = fmaf(c, bf2f((unsigned short)(w[k] & 0xffff)), a[2 * k]);
    a[2 * k + 1] = fmaf(c, bf2f((unsigned short)(w[k] >> 16)),    a[2 * k + 1]);
  }
}

__device__ __forceinline__ uint4 pack8(const float* a, bool relu) {
  unsigned ov[4];
#pragma unroll
  for (int k = 0; k < 4; ++k) {
    float lo = a[2 * k], hi = a[2 * k + 1];
    if (relu) { lo = fmaxf(lo, 0.f); hi = fmaxf(hi, 0.f); }
    ov[k] = (unsigned)f2bf(lo) | ((unsigned)f2bf(hi) << 16);
  }
  uint4 o; o.x = ov[0]; o.y = ov[1]; o.z = ov[2]; o.w = ov[3];
  return o;
}

__global__ void k_gat_agg(const unsigned short* __restrict__ fneigh,
                          const float* __restrict__ attS, const float* __restrict__ attN,
                          const int* __restrict__ rowptr, const int2* __restrict__ edge,
                          unsigned short* __restrict__ out, int N)
{
  const int n = blockIdx.x * 4 + (threadIdx.x >> 6);
  if (n >= N) return;                         // wave-uniform (n per wave)
  const int lane = threadIdx.x & 63;
  const int half = lane >> 5;                 // which edge of the pair
  const int c32  = lane & 31;                 // 8 cols/lane
  const int head = c32 >> 2;                  // 32 cols/head
  const float as = attS[(size_t)n * NHEAD + head];
  float a[8] = {};
  int p = rowptr[n];
  const int e = rowptr[n + 1];
  for (; p + 3 < e; p += 4) {                 // 4 edges / iter (2 pairs)
    const int2 ea = edge[p + half];
    const int2 eb = edge[p + 2 + half];
    const float ca = (as + attN[(size_t)ea.x * NHEAD + head]) * __int_as_float(ea.y);
    const float cb = (as + attN[(size_t)eb.x * NHEAD + head]) * __int_as_float(eb.y);
    const uint4 fa = *(const uint4*)(fneigh + (size_t)ea.x * D + c32 * 8);
    const uint4 fb = *(const uint4*)(fneigh + (size_t)eb.x * D + c32 * 8);
    acc8(a, fa, ca);
    acc8(a, fb, cb);
  }
  if (p + 1 < e) {                            // one full pair
    const int2 ea = edge[p + half];
    const float ca = (as + attN[(size_t)ea.x * NHEAD + head]) * __int_as_float(ea.y);
    const uint4 fa = *(const uint4*)(fneigh + (size_t)ea.x * D + c32 * 8);
    acc8(a, fa, ca);
    p += 2;
  }
  if (p < e && half == 0) {                   // last single edge: lower half
    const int2 ea = edge[p];
    const float ca = (as + attN[(size_t)ea.x * NHEAD + head]) * __int_as_float(ea.y);
    const uint4 fa = *(const uint4*)(fneigh + (size_t)ea.x * D + c32 * 8);
    acc8(a, fa, ca);
  }
#pragma unroll
  for (int k = 0; k < 8; ++k) a[k] += __shfl_xor(a[k], 32);
  if (half == 0)
    *(uint4*)(out + (size_t)n * D + c32 * 8) = pack8(a, false);
}

__global__ void k_gcn_agg(const unsigned short* __restrict__ Hm,
                          const int* __restrict__ rowptr, const int2* __restrict__ edge,
                          unsigned short* __restrict__ out, int N)
{
  const int n = blockIdx.x * 4 + (threadIdx.x >> 6);
  if (n >= N) return;                         // wave-uniform (n per wave)
  const int lane = threadIdx.x & 63;
  const int half = lane >> 5;
  const int c32  = lane & 31;
  float a[8] = {};
  int p = rowptr[n];
  const int e = rowptr[n + 1];
  for (; p + 3 < e; p += 4) {                 // 4 edges / iter (2 pairs)
    const int2 ea = edge[p + half];
    const int2 eb = edge[p + 2 + half];
    const uint4 fa = *(const uint4*)(Hm + (size_t)ea.x * D + c32 * 8);
    const uint4 fb = *(const uint4*)(Hm + (size_t)eb.x * D + c32 * 8);
    acc8(a, fa, __int_as_float(ea.y));
    acc8(a, fb, __int_as_float(eb.y));
  }
  if (p + 1 < e) {                            // one full pair
    const int2 ea = edge[p + half];
    const uint4 fa = *(const uint4*)(Hm + (size_t)ea.x * D + c32 * 8);
    acc8(a, fa, __int_as_float(ea.y));
    p += 2;
  }
  if (p < e && half == 0) {                   // last single edge: lower half
    const int2 ea = edge[p];
    const uint4 fa = *(const uint4*)(Hm + (size_t)ea.x * D + c32 * 8);
    acc8(a, fa, __int_as_float(ea.y));
  }
#pragma unroll
  for (int k = 0; k < 8; ++k) a[k] += __shfl_xor(a[k], 32);
  if (half == 0)
    *(uint4*)(out + (size_t)n * D + c32 * 8) = pack8(a, true);  // relu pre-BN
}

// ---------------- BatchNorm stats: 1024 blocks, 64-slot replicated sums -----
// 16 contributors/address; 524K atomics total (amortized over ~49 rows/block).
__launch_bounds__(256)
__global__ void k_bn_stats(const unsigned short* __restrict__ X, float* __restrict__ sums, int M)
{
  __shared__ float ls[256][8];
  __shared__ float lq[256][8];
  const int t = threadIdx.x, cg = t & 31, rg = t >> 5;
  float s[8] = {}, q[8] = {};
  for (int r = blockIdx.x * 8 + rg; r < M; r += gridDim.x * 8) {
    const uint4 f = *(const uint4*)(X + (size_t)r * D + cg * 8);
    const unsigned w[4] = {f.x, f.y, f.z, f.w};
#pragma unroll
    for (int k = 0; k < 4; ++k) {
      const float lo = bf2f((unsigned short)(w[k] & 0xffff));
      const float hi = bf2f((unsigned short)(w[k] >> 16));
      s[2 * k]     += lo; q[2 * k]     = fmaf(lo, lo, q[2 * k]);
      s[2 * k + 1] += hi; q[2 * k + 1] = fmaf(hi, hi, q[2 * k + 1]);
    }
  }
#pragma unroll
  for (int k = 0; k < 8; ++k) { ls[t][k] = s[k]; lq[t][k] = q[k]; }
  __syncthreads();
  if (rg == 0) {
    float* slot = sums + (size_t)(blockIdx.x & (NSLOT - 1)) * 2 * D;
#pragma unroll
    for (int g = 1; g < 8; ++g)
#pragma unroll
      for (int k = 0; k < 8; ++k) { s[k] += ls[cg + 32 * g][k]; q[k] += lq[cg + 32 * g][k]; }
#pragma unroll
    for (int k = 0; k < 8; ++k) {
      atomicAdd(&slot[cg * 8 + k], s[k]);
      atomicAdd(&slot[D + cg * 8 + k], q[k]);
    }
  }
}

// ---------------- Classifier (BN folded in; murs = mu[256]|rs[256]) ---------
__global__ void k_classifier(const unsigned short* __restrict__ F, const float* __restrict__ W,
                             const float* __restrict__ murs, const float* __restrict__ cls_b,
                             float* __restrict__ out, int N, int baseRow, int initMode)
{
  __shared__ float smu[D], srs[D];
  const int t = threadIdx.x;
  smu[t] = murs[t];
  srs[t] = murs[D + t];
  __syncthreads();

  const int n = blockIdx.x * 8 + (t >> 5);
  if (n >= N) return;
  const int lane = t & 31;
  const uint4 f = *(const uint4*)(F + (size_t)n * D + lane * 8);
  const unsigned w[4] = {f.x, f.y, f.z, f.w};
  float fv[8];
#pragma unroll
  for (int k = 0; k < 4; ++k) {
    fv[2 * k]     = (bf2f((unsigned short)(w[k] & 0xffff)) - smu[lane * 8 + 2 * k])     * srs[lane * 8 + 2 * k];
    fv[2 * k + 1] = (bf2f((unsigned short)(w[k] >> 16))    - smu[lane * 8 + 2 * k + 1]) * srs[lane * 8 + 2 * k + 1];
  }
  const float* Wr = W + (size_t)(baseRow + lane * 8) * NCLS;
  float p[NCLS];
#pragma unroll
  for (int c = 0; c < NCLS; ++c) {
    float s = 0.f;
#pragma unroll
    for (int k = 0; k < 8; ++k) s = fmaf(fv[k], Wr[k * NCLS + c], s);
    p[c] = s;
  }
#pragma unroll
  for (int m = 1; m < 32; m <<= 1)
#pragma unroll
    for (int c = 0; c < NCLS; ++c) p[c] += __shfl_xor(p[c], m);
  if (lane == 0) {
    float* o = out + (size_t)n * NCLS;
    if (initMode) {
#pragma unroll
      for (int c = 0; c < NCLS; ++c) o[c] = p[c] + cls_b[c];
    } else {
#pragma unroll
      for (int c = 0; c < NCLS; ++c) o[c] += p[c];
    }
  }
}

// ---------------------------------------------------------------------------
extern "C" void kernel_launch(void* const* d_in, const int* in_sizes, int n_in,
                              void* d_out, int out_size, void* d_ws, size_t ws_size,
                              hipStream_t stream)
{
  const float* f_in   = (const float*)d_in[0];
  const int*   erow   = (const int*)d_in[1];
  const int*   ecol   = (const int*)d_in[2];
  const float* eval   = (const float*)d_in[3];
  const float* gat_Ws = (const float*)d_in[4];
  const float* gat_bs = (const float*)d_in[5];
  const float* gat_Wn = (const float*)d_in[6];
  const float* gat_bn = (const float*)d_in[7];
  const float* gat_as = (const float*)d_in[8];
  const float* gat_an = (const float*)d_in[9];
  const float* gcn_W  = (const float*)d_in[10];
  const float* gcn_b  = (const float*)d_in[11];
  const float* self_W = (const float*)d_in[12];
  const float* self_b = (const float*)d_in[13];
  const float* cls_W  = (const float*)d_in[14];
  const float* cls_b  = (const float*)d_in[15];
  float* out = (float*)d_out;

  const int N  = in_sizes[0] / D;      // 50000
  const int E  = in_sizes[1] / 4;      // 400000
  const int E4 = 4 * E, N4 = 4 * N;
  const size_t ND = (size_t)N * D;

  // ---- workspace carve-up (byte-identical footprint to round 3) ----
  unsigned short* bufA = (unsigned short*)d_ws;
  unsigned short* bufB = bufA + ND;
  unsigned short* bufC = bufB + ND;
  unsigned short* finB = bufC + ND;
  unsigned short* Wt   = finB + ND;                 // 11*65536
  float* attS   = (float*)(Wt + (size_t)11 * D * D);
  float* attN   = attS + (size_t)N * NHEAD;
  int*   scanTmp= (int*)(attN + (size_t)N * NHEAD);
  int*   blkSum = scanTmp + N4;
  int*   rowptr = blkSum + 1024;
  int2*  edge   = (int2*)(rowptr + (N4 + 4));
  // zeroed region: cnt[4N] | fill[4N]
  int*   cnt    = (int*)(edge + E4);
  int*   fill   = cnt + N4;
  // foldB + murs alias scanTmp (dead after CSR build)
  float* foldB    = (float*)scanTmp;               // 5*256 floats
  float* murs     = (float*)scanTmp + 2048;        // 9*512 floats
  // 64-slot stats sums alias cnt/fill (dead after k_scatter):
  // 9 ids * 64 slots * 2*D floats = 1.18 MB <= 1.6 MB
  float* slotSums = (float*)cnt;
  const size_t zero_bytes = (size_t)(2 * N4) * sizeof(int);
  const size_t slot_bytes = (size_t)9 * NSLOT * 2 * D * sizeof(float);

  const dim3 gemm_grid((N + 127) / 128, D / 128);
  const dim3 gemm_grid2((N + 127) / 128, 4);    // merged GAT: 512 cols
  const dim3 cvtw_grid(11, 8, 8);
  const int nb8   = (N + 7) / 8;
  const int nb4   = (N + 3) / 4;       // agg: 1 node/wave, 4 waves/block
  const int scanG = (N4 + 255) / 256;

  hipMemsetAsync(cnt, 0, zero_bytes, stream);

  // conversions
  k_cvt  <<<(int)(ND / 8 + 255) / 256, 256, 0, stream>>>(f_in, finB, (int)(ND / 8));
  k_cvt_w<<<cvtw_grid, 256, 0, stream>>>(gat_Ws, gat_Wn, gcn_W, self_W, Wt);

  // batched CSR for 4 adjacencies
  k_count   <<<(E4 + 255) / 256, 256, 0, stream>>>(erow, cnt, E4, E, N);
  k_scan_blk<<<scanG, 256, 0, stream>>>(cnt, scanTmp, blkSum, N4);
  k_scan_top<<<1, 1024, 0, stream>>>(blkSum, scanG);
  k_scan_fin<<<scanG, 256, 0, stream>>>(scanTmp, blkSum, rowptr, N4);
  k_scatter <<<(E4 + 255) / 256, 256, 0, stream>>>(erow, ecol, eval, rowptr, fill,
                                                   edge, E4, E, N);

  // cnt/fill and scanTmp are dead now — zero the aliased slot-sums region
  hipMemsetAsync(slotSums, 0, slot_bytes, stream);

  const size_t WM = (size_t)D * D;
  auto sumsOf = [&](int id) { return slotSums + (size_t)id * NSLOT * 2 * D; };
  auto mursOf = [&](int id) { return murs + (size_t)id * 2 * D; };
  auto stats = [&](unsigned short* X, int id) {
    k_bn_stats<<<1024, 256, 0, stream>>>(X, sumsOf(id), N);
  };

  // ===================== GAT branch (adjacency 0) ==========================
  {
    const int* rp = rowptr;
    // layer 0: MERGED GEMM — slab0 = Ws(att only), slab1 = Wn -> bufB
    k_gemm_mfma<<<gemm_grid2, 256, 0, stream>>>(finB, Wt + 0 * WM, gat_bs, gat_bn,
                                                bufB, N, 1,
                                                gat_as, gat_an, attS, attN, nullptr);
    k_gat_agg  <<<nb4, 256, 0, stream>>>(bufB, attS, attN, rp, edge, bufC, N);
    stats(bufC, 0);
    // fold BN(0) into layer-1 weights (both Ws and Wn consume bufC)
    k_fold_w<<<D, 256, 0, stream>>>(gat_Ws + (size_t)NHEAD * D * 32, gat_bs + D,
                                    sumsOf(0), Wt + 2 * WM, foldB + 0 * D, 0, N);
    k_fold_w<<<D, 256, 0, stream>>>(gat_Wn + (size_t)NHEAD * D * 32, gat_bn + D,
                                    sumsOf(0), Wt + 3 * WM, foldB + 1 * D, 0, N);
    // layer 1: MERGED GEMM — slab0 = Ws'(att only), slab1 = Wn' -> bufB
    k_gemm_mfma<<<gemm_grid2, 256, 0, stream>>>(bufC, Wt + 2 * WM, foldB + 0 * D,
                                                foldB + 1 * D, bufB, N, 1,
                                                gat_as + D, gat_an + D, attS, attN, nullptr);
    k_gat_agg  <<<nb4, 256, 0, stream>>>(bufB, attS, attN, rp, edge, bufA, N);
    stats(bufA, 1);
    k_collapse<<<1, 256, 0, stream>>>(sumsOf(1), mursOf(1), N);
    k_classifier<<<nb8, 256, 0, stream>>>(bufA, cls_W, mursOf(1), cls_b, out, N, 0, 1);
  }

  // ===================== 3 GCN branches (adjacency 1..3) ===================
  for (int g = 0; g < 3; ++g) {
    const int* rp = rowptr + (size_t)(g + 1) * N;
    const float* bg = gcn_b + (size_t)g * 2 * D;
    k_gemm_mfma<<<gemm_grid, 256, 0, stream>>>(finB, Wt + (4 + 2 * g) * WM, bg, bg,
                                               bufA, N, 0,
                                               nullptr, nullptr, nullptr, nullptr, nullptr);
    k_gcn_agg  <<<nb4, 256, 0, stream>>>(bufA, rp, edge, bufB, N);
    stats(bufB, 2 + 2 * g);
    // fold BN(2+2g) into layer-2 weights
    k_fold_w<<<D, 256, 0, stream>>>(gcn_W + (size_t)(2 * g + 1) * D * D, bg + D,
                                    sumsOf(2 + 2 * g),
                                    Wt + (5 + 2 * g) * WM, foldB + (2 + g) * D, 1, N);
    k_gemm_mfma<<<gemm_grid, 256, 0, stream>>>(bufB, Wt + (5 + 2 * g) * WM,
                                               foldB + (2 + g) * D, foldB + (2 + g) * D,
                                               bufA, N, 0,
                                               nullptr, nullptr, nullptr, nullptr, nullptr);
    k_gcn_agg  <<<nb4, 256, 0, stream>>>(bufA, rp, edge, bufB, N);
    stats(bufB, 3 + 2 * g);
    k_collapse<<<1, 256, 0, stream>>>(sumsOf(3 + 2 * g), mursOf(3 + 2 * g), N);
    k_classifier<<<nb8, 256, 0, stream>>>(bufB, cls_W, mursOf(3 + 2 * g), cls_b,
                                          out, N, (1 + g) * D, 0);
  }

  // ===================== self perceptron (stats fused, 64-slot) ============
  k_gemm_mfma<<<gemm_grid, 256, 0, stream>>>(finB, Wt + 10 * WM, self_b, self_b,
                                             bufA, N, 1,
                                             nullptr, nullptr, nullptr, nullptr,
                                             sumsOf(8));
  k_collapse<<<1, 256, 0, stream>>>(sumsOf(8), mursOf(8), N);
  k_classifier<<<nb8, 256, 0, stream>>>(bufA, cls_W, mursOf(8), cls_b, out, N, 4 * D, 0);
}

// Round 12
// 1171.108 us; speedup vs baseline: 2.2970x; 1.0714x over previous
//
#include <hip/hip_runtime.h>

// ---------------------------------------------------------------------------
// ERC GNN forward — round 15 (exact r11 restore + ONE isolated change):
//  * LESSON (r13/r14): 1024-blk/64-slot stats + k_collapse + 64-slot fold_w
//    bundle regressed −84µs vs r11. Cold-kernel "improvements" reverted.
//  * r11 config restored: k_bn_stats 256 blocks / NSLOT=8; classifier sums
//    the 8 slots inline; fold_w reads 8 slots; no k_collapse.
//  * ONLY change vs r11: k_cvt_w = LDS 32x32 tile transpose (old version
//    read weights at 1KB stride -> ~45MB line amplification; bit-identical
//    output, single cold dispatch -> cleanly attributable).
// ---------------------------------------------------------------------------

constexpr int D     = 256;
constexpr int NHEAD = 8;
constexpr int NCLS  = 7;
constexpr int NSLOT = 8;                    // bn-stats slot replication
constexpr float BN_EPS = 1e-9f;

typedef short  s16x8 __attribute__((ext_vector_type(8)));
typedef float  f32x4 __attribute__((ext_vector_type(4)));

__device__ __forceinline__ unsigned short f2bf(float f) {
  unsigned int u = __builtin_bit_cast(unsigned int, f);
  u += 0x7FFFu + ((u >> 16) & 1u);          // round-to-nearest-even
  return (unsigned short)(u >> 16);
}
__device__ __forceinline__ float bf2f(unsigned short h) {
  unsigned int u = ((unsigned int)h) << 16;
  return __builtin_bit_cast(float, u);
}

__device__ __forceinline__ void gload_lds16(const void* g, void* l) {
  __builtin_amdgcn_global_load_lds(
      (const __attribute__((address_space(1))) unsigned int*)g,
      (__attribute__((address_space(3))) unsigned int*)l, 16, 0, 0);
}

// ---------------- bf16 MFMA GEMM: C[M,cols] = A[M,256] @ Wt^T + bias --------
// Merged-GAT mode (attS!=null, grid.y=4 over 512 cols):
//   cols [0,256): att epilogue only; cols [256,512): relu path, bias=biasB.
// Normal mode: optional slot-replicated BN stats epilogue (bnOut).
__launch_bounds__(256)
__global__ void k_gemm_mfma(const unsigned short* __restrict__ A,
                            const unsigned short* __restrict__ Wt,
                            const float* __restrict__ bias,
                            const float* __restrict__ biasB,
                            unsigned short* __restrict__ C,
                            int M, int doRelu,
                            const float* __restrict__ a_s, const float* __restrict__ a_n,
                            float* __restrict__ attS, float* __restrict__ attN,
                            float* __restrict__ bnOut)
{
  __shared__ unsigned short As[128 * 32];
  __shared__ unsigned short Bs[128 * 32];
  const int t = threadIdx.x;
  const int wave = t >> 6, lane = t & 63;
  const int quad = lane >> 4, l16 = lane & 15;
  const int wm = (wave & 1) * 64, wn = (wave >> 1) * 64;
  const int bm = blockIdx.x * 128, bn = blockIdx.y * 128;

  f32x4 acc[4][4] = {};

  const int rA0 = wave * 32 + (lane >> 2);
  const int rA1 = rA0 + 16;
  const int sub = (lane & 3) * 8;
  const unsigned short* gA0 = A  + (size_t)min(bm + rA0, M - 1) * D + sub;
  const unsigned short* gA1 = A  + (size_t)min(bm + rA1, M - 1) * D + sub;
  const unsigned short* gB0 = Wt + (size_t)(bn + rA0) * D + sub;
  const unsigned short* gB1 = Wt + (size_t)(bn + rA1) * D + sub;
  unsigned short* lA0 = &As[wave * 1024];
  unsigned short* lA1 = &As[wave * 1024 + 512];
  unsigned short* lB0 = &Bs[wave * 1024];
  unsigned short* lB1 = &Bs[wave * 1024 + 512];

  for (int k0 = 0; k0 < D; k0 += 32) {
    gload_lds16(gA0 + k0, lA0);
    gload_lds16(gA1 + k0, lA1);
    gload_lds16(gB0 + k0, lB0);
    gload_lds16(gB1 + k0, lB1);
    __syncthreads();
    s16x8 af[4], bf[4];
#pragma unroll
    for (int mi = 0; mi < 4; ++mi)
      af[mi] = *(const s16x8*)(&As[(wm + mi * 16 + l16) * 32 + quad * 8]);
#pragma unroll
    for (int nj = 0; nj < 4; ++nj)
      bf[nj] = *(const s16x8*)(&Bs[(wn + nj * 16 + l16) * 32 + quad * 8]);
#pragma unroll
    for (int mi = 0; mi < 4; ++mi)
#pragma unroll
      for (int nj = 0; nj < 4; ++nj)
        acc[mi][nj] = __builtin_amdgcn_mfma_f32_16x16x32_bf16(af[mi], bf[nj], acc[mi][nj], 0, 0, 0);
    __syncthreads();
  }

  // C/D layout: col = l16, row = quad*4 + reg (m89-verified)
  const bool attSlab = (attS != nullptr) && (bn < 256);
  if (attSlab) {
    const int hb = (bn + wn) >> 5;
#pragma unroll
    for (int mi = 0; mi < 4; ++mi) {
#pragma unroll
      for (int h = 0; h < 2; ++h) {
        float ps[4] = {}, pn[4] = {};
#pragma unroll
        for (int j = 0; j < 2; ++j) {
          const int nj = h * 2 + j;
          const int col = bn + wn + nj * 16 + l16;
          const float bv = bias[col];
          const float av = a_s[col], nv = a_n[col];
#pragma unroll
          for (int r = 0; r < 4; ++r) {
            const float v = fmaxf(acc[mi][nj][r] + bv, 0.f);
            ps[r] = fmaf(v, av, ps[r]);
            pn[r] = fmaf(v, nv, pn[r]);
          }
        }
#pragma unroll
        for (int m = 1; m < 16; m <<= 1)
#pragma unroll
          for (int r = 0; r < 4; ++r) {
            ps[r] += __shfl_xor(ps[r], m);
            pn[r] += __shfl_xor(pn[r], m);
          }
        if (l16 == 0) {
#pragma unroll
          for (int r = 0; r < 4; ++r) {
            const int row = bm + wm + mi * 16 + quad * 4 + r;
            if (row < M) {
              const float s_ = ps[r], n_ = pn[r];
              attS[(size_t)row * NHEAD + hb + h] = (s_ > 0.f) ? s_ : 0.2f * s_;
              attN[(size_t)row * NHEAD + hb + h] = (n_ > 0.f) ? n_ : 0.2f * n_;
            }
          }
        }
      }
    }
  } else {
    // normal path; in merged-GAT mode this is the Wn slab (cols 256..511)
    const int cBase = (attS != nullptr) ? 256 : 0;
    const float* bsrc = (attS != nullptr) ? biasB : bias;
    float cs[4] = {}, cq[4] = {};
#pragma unroll
    for (int nj = 0; nj < 4; ++nj) {
      const int col = bn + wn + nj * 16 + l16;       // Wt row index
      const int cw  = col - cBase;                   // output col
      const float bv = bsrc[cw];
#pragma unroll
      for (int mi = 0; mi < 4; ++mi) {
#pragma unroll
        for (int r = 0; r < 4; ++r) {
          const int row = bm + wm + mi * 16 + quad * 4 + r;
          if (row < M) {
            float v = acc[mi][nj][r] + bv;
            if (doRelu) v = fmaxf(v, 0.f);
            const unsigned short u = f2bf(v);
            C[(size_t)row * D + cw] = u;
            if (bnOut) {
              const float w = bf2f(u);
              cs[nj] += w;
              cq[nj] = fmaf(w, w, cq[nj]);
            }
          }
        }
      }
    }
    if (bnOut) {
      // quad-reduce (lanes l16,+16,+32,+48 share a column), slot-replicated
#pragma unroll
      for (int nj = 0; nj < 4; ++nj) {
        cs[nj] += __shfl_xor(cs[nj], 16);
        cq[nj] += __shfl_xor(cq[nj], 16);
        cs[nj] += __shfl_xor(cs[nj], 32);
        cq[nj] += __shfl_xor(cq[nj], 32);
      }
      if (quad == 0) {
        float* slot = bnOut + (size_t)(blockIdx.x & (NSLOT - 1)) * 2 * D;
#pragma unroll
        for (int nj = 0; nj < 4; ++nj) {
          const int col = bn + wn + nj * 16 + l16;
          atomicAdd(&slot[col], cs[nj]);
          atomicAdd(&slot[D + col], cq[nj]);
        }
      }
    }
  }
}

// ---------------- conversions -----------------------------------------------
__global__ void k_cvt(const float* __restrict__ src, unsigned short* __restrict__ dst, int n8)
{
  const int i = blockIdx.x * 256 + threadIdx.x;
  if (i >= n8) return;
  const float4 a = *(const float4*)(src + (size_t)i * 8);
  const float4 b = *(const float4*)(src + (size_t)i * 8 + 4);
  uint4 o;
  o.x = (unsigned)f2bf(a.x) | ((unsigned)f2bf(a.y) << 16);
  o.y = (unsigned)f2bf(a.z) | ((unsigned)f2bf(a.w) << 16);
  o.z = (unsigned)f2bf(b.x) | ((unsigned)f2bf(b.y) << 16);
  o.w = (unsigned)f2bf(b.z) | ((unsigned)f2bf(b.w) << 16);
  *(uint4*)(dst + (size_t)i * 8) = o;
}

// LDS tile-transposed weight conversion: reads and writes both coalesced.
// grid = (11 m-slabs, 8 j-tiles, 8 d-tiles), block = 256. Bit-identical to
// the old strided version (same f2bf on the same source element).
__global__ void k_cvt_w(const float* __restrict__ gat_Ws, const float* __restrict__ gat_Wn,
                        const float* __restrict__ gcn_W, const float* __restrict__ self_W,
                        unsigned short* __restrict__ Wt)
{
  __shared__ float tile[32][33];
  const int m = blockIdx.x, jt = blockIdx.y, dt = blockIdx.z;
  const int tx = threadIdx.x & 31, ty = threadIdx.x >> 5;
#pragma unroll
  for (int r = 0; r < 4; ++r) {
    const int dl = ty * 4 + r;                 // d_local
    const int d  = dt * 32 + dl;
    float v;
    if (m < 4) {
      const int l = m >> 1;
      const float* W = (m & 1) ? gat_Wn : gat_Ws;           // [L,H,D,DH]
      v = W[(((size_t)l * NHEAD + jt) * D + d) * 32 + tx];  // j>>5=jt, j&31=tx
    } else if (m < 10) {
      v = gcn_W[((size_t)(m - 4) * D + d) * D + jt * 32 + tx];
    } else {
      v = self_W[(size_t)d * D + jt * 32 + tx];
    }
    tile[dl][tx] = v;                          // [d_local][j_local]
  }
  __syncthreads();
#pragma unroll
  for (int r = 0; r < 4; ++r) {
    const int jl = ty * 4 + r;                 // j_local
    const int j  = jt * 32 + jl;
    const int d  = dt * 32 + tx;
    Wt[((size_t)m * D + j) * D + d] = f2bf(tile[tx][jl]);
  }
}

// ---------------- BN-fold: W'[j,d] = rs_d*W[j,d]; b'[j] = b[j]-Σ mu_d*W'[j,d]
// sums = 8-slot base. mode 0: GAT layout [H,D,DH]; mode 1: GCN [D_in,D_out]
__global__ void k_fold_w(const float* __restrict__ srcW, const float* __restrict__ srcB,
                         const float* __restrict__ sums, unsigned short* __restrict__ dstW,
                         float* __restrict__ dstB, int mode, int Nn)
{
  __shared__ float red[256];
  const int j = blockIdx.x;      // out col
  const int d = threadIdx.x;     // in dim (BN axis)
  float sAcc = 0.f, qAcc = 0.f;
#pragma unroll
  for (int s8 = 0; s8 < NSLOT; ++s8) {
    sAcc += sums[s8 * 2 * D + d];
    qAcc += sums[s8 * 2 * D + D + d];
  }
  const float inv = 1.f / (float)Nn;
  const float m_ = sAcc * inv;
  const float rs = rsqrtf(qAcc * inv - m_ * m_ + BN_EPS);
  float w;
  if (mode == 0) w = srcW[(((size_t)(j >> 5)) * D + d) * 32 + (j & 31)];
  else           w = srcW[(size_t)d * D + j];
  const unsigned short q = f2bf(w * rs);
  dstW[(size_t)j * D + d] = q;
  red[d] = m_ * bf2f(q);         // use quantized weight so fold is exact vs GEMM
  __syncthreads();
  for (int off = 128; off > 0; off >>= 1) {
    if (d < off) red[d] += red[d + off];
    __syncthreads();
  }
  if (d == 0) dstB[j] = srcB[j] - red[0];
}

// ---------------- batched CSR build (4 adjacencies) --------------------------
__global__ void k_count(const int* __restrict__ rows, int* __restrict__ cnt, int E4, int E, int N)
{
  const int i = blockIdx.x * 256 + threadIdx.x;
  if (i < E4) atomicAdd(&cnt[(i / E) * N + rows[i]], 1);
}

__global__ void k_scan_blk(const int* __restrict__ in, int* __restrict__ scanTmp,
                           int* __restrict__ blkSum, int n)
{
  __shared__ int buf[256];
  const int t = threadIdx.x, i = blockIdx.x * 256 + t;
  const int v = (i < n) ? in[i] : 0;
  buf[t] = v; __syncthreads();
  for (int off = 1; off < 256; off <<= 1) {
    const int x = (t >= off) ? buf[t - off] : 0;
    __syncthreads();
    buf[t] += x; __syncthreads();
  }
  if (i < n) scanTmp[i] = buf[t];
  if (t == 255) blkSum[blockIdx.x] = buf[255];
}

__global__ void k_scan_top(int* __restrict__ blkSum, int G)
{
  __shared__ int buf[1024];
  const int t = threadIdx.x;
  const int v = (t < G) ? blkSum[t] : 0;
  buf[t] = v; __syncthreads();
  for (int off = 1; off < 1024; off <<= 1) {
    const int x = (t >= off) ? buf[t - off] : 0;
    __syncthreads();
    buf[t] += x; __syncthreads();
  }
  if (t < G) blkSum[t] = buf[t] - v;
}

__global__ void k_scan_fin(const int* __restrict__ scanTmp, const int* __restrict__ blkOff,
                           int* __restrict__ rowptr, int n)
{
  const int i = blockIdx.x * 256 + threadIdx.x;
  if (i < n) rowptr[i + 1] = scanTmp[i] + blkOff[blockIdx.x];
  if (i == 0) rowptr[0] = 0;
}

// packed scatter: one 8B store per edge {col, val-bits}
__global__ void k_scatter(const int* __restrict__ rows, const int* __restrict__ cols,
                          const float* __restrict__ vals,
                          const int* __restrict__ rowptr, int* __restrict__ fill,
                          int2* __restrict__ edge, int E4, int E, int N)
{
  const int i = blockIdx.x * 256 + threadIdx.x;
  if (i >= E4) return;
  const int g = (i / E) * N + rows[i];
  const int p = rowptr[g] + atomicAdd(&fill[g], 1);
  edge[p] = make_int2(cols[i], __float_as_int(vals[i]));
}

// ---------------- Aggregations: 1 node/WAVE, half-waves split edge pairs ----
__device__ __forceinline__ void acc8(float* a, uint4 f, float c) {
  const unsigned w[4] = {f.x, f.y, f.z, f.w};
#pragma unroll
  for (int k = 0; k < 4; ++k) {
    a[2 * k]     = fmaf(c, bf2f((unsigned short)(w[k] & 0xffff)), a[2 * k]);
    a[2 * k + 1] = fmaf(c, bf2f((unsigned short)(w[k] >> 16)),    a[2 * k + 1]);
  }
}

__device__ __forceinline__ uint4 pack8(const float* a, bool relu) {
  unsigned ov[4];
#pragma unroll
  for (int k = 0; k < 4; ++k) {
    float lo = a[2 * k], hi = a[2 * k + 1];
    if (relu) { lo = fmaxf(lo, 0.f); hi = fmaxf(hi, 0.f); }
    ov[k] = (unsigned)f2bf(lo) | ((unsigned)f2bf(hi) << 16);
  }
  uint4 o; o.x = ov[0]; o.y = ov[1]; o.z = ov[2]; o.w = ov[3];
  return o;
}

__global__ void k_gat_agg(const unsigned short* __restrict__ fneigh,
                          const float* __restrict__ attS, const float* __restrict__ attN,
                          const int* __restrict__ rowptr, const int2* __restrict__ edge,
                          unsigned short* __restrict__ out, int N)
{
  const int n = blockIdx.x * 4 + (threadIdx.x >> 6);
  if (n >= N) return;                         // wave-uniform (n per wave)
  const int lane = threadIdx.x & 63;
  const int half = lane >> 5;                 // which edge of the pair
  const int c32  = lane & 31;                 // 8 cols/lane
  const int head = c32 >> 2;                  // 32 cols/head
  const float as = attS[(size_t)n * NHEAD + head];
  float a[8] = {};
  int p = rowptr[n];
  const int e = rowptr[n + 1];
  for (; p + 3 < e; p += 4) {                 // 4 edges / iter (2 pairs)
    const int2 ea = edge[p + half];
    const int2 eb = edge[p + 2 + half];
    const float ca = (as + attN[(size_t)ea.x * NHEAD + head]) * __int_as_float(ea.y);
    const float cb = (as + attN[(size_t)eb.x * NHEAD + head]) * __int_as_float(eb.y);
    const uint4 fa = *(const uint4*)(fneigh + (size_t)ea.x * D + c32 * 8);
    const uint4 fb = *(const uint4*)(fneigh + (size_t)eb.x * D + c32 * 8);
    acc8(a, fa, ca);
    acc8(a, fb, cb);
  }
  if (p + 1 < e) {                            // one full pair
    const int2 ea = edge[p + half];
    const float ca = (as + attN[(size_t)ea.x * NHEAD + head]) * __int_as_float(ea.y);
    const uint4 fa = *(const uint4*)(fneigh + (size_t)ea.x * D + c32 * 8);
    acc8(a, fa, ca);
    p += 2;
  }
  if (p < e && half == 0) {                   // last single edge: lower half
    const int2 ea = edge[p];
    const float ca = (as + attN[(size_t)ea.x * NHEAD + head]) * __int_as_float(ea.y);
    const uint4 fa = *(const uint4*)(fneigh + (size_t)ea.x * D + c32 * 8);
    acc8(a, fa, ca);
  }
#pragma unroll
  for (int k = 0; k < 8; ++k) a[k] += __shfl_xor(a[k], 32);
  if (half == 0)
    *(uint4*)(out + (size_t)n * D + c32 * 8) = pack8(a, false);
}

__global__ void k_gcn_agg(const unsigned short* __restrict__ Hm,
                          const int* __restrict__ rowptr, const int2* __restrict__ edge,
                          unsigned short* __restrict__ out, int N)
{
  const int n = blockIdx.x * 4 + (threadIdx.x >> 6);
  if (n >= N) return;                         // wave-uniform (n per wave)
  const int lane = threadIdx.x & 63;
  const int half = lane >> 5;
  const int c32  = lane & 31;
  float a[8] = {};
  int p = rowptr[n];
  const int e = rowptr[n + 1];
  for (; p + 3 < e; p += 4) {                 // 4 edges / iter (2 pairs)
    const int2 ea = edge[p + half];
    const int2 eb = edge[p + 2 + half];
    const uint4 fa = *(const uint4*)(Hm + (size_t)ea.x * D + c32 * 8);
    const uint4 fb = *(const uint4*)(Hm + (size_t)eb.x * D + c32 * 8);
    acc8(a, fa, __int_as_float(ea.y));
    acc8(a, fb, __int_as_float(eb.y));
  }
  if (p + 1 < e) {                            // one full pair
    const int2 ea = edge[p + half];
    const uint4 fa = *(const uint4*)(Hm + (size_t)ea.x * D + c32 * 8);
    acc8(a, fa, __int_as_float(ea.y));
    p += 2;
  }
  if (p < e && half == 0) {                   // last single edge: lower half
    const int2 ea = edge[p];
    const uint4 fa = *(const uint4*)(Hm + (size_t)ea.x * D + c32 * 8);
    acc8(a, fa, __int_as_float(ea.y));
  }
#pragma unroll
  for (int k = 0; k < 8; ++k) a[k] += __shfl_xor(a[k], 32);
  if (half == 0)
    *(uint4*)(out + (size_t)n * D + c32 * 8) = pack8(a, true);  // relu pre-BN
}

// ---------------- BatchNorm stats: 8-slot replicated sums -------------------
// 256 blocks; block b atomics into slot (b & 7) -> 32 contributors/address.
__launch_bounds__(256)
__global__ void k_bn_stats(const unsigned short* __restrict__ X, float* __restrict__ sums, int M)
{
  __shared__ float ls[256][8];
  __shared__ float lq[256][8];
  const int t = threadIdx.x, cg = t & 31, rg = t >> 5;
  float s[8] = {}, q[8] = {};
  for (int r = blockIdx.x * 8 + rg; r < M; r += gridDim.x * 8) {
    const uint4 f = *(const uint4*)(X + (size_t)r * D + cg * 8);
    const unsigned w[4] = {f.x, f.y, f.z, f.w};
#pragma unroll
    for (int k = 0; k < 4; ++k) {
      const float lo = bf2f((unsigned short)(w[k] & 0xffff));
      const float hi = bf2f((unsigned short)(w[k] >> 16));
      s[2 * k]     += lo; q[2 * k]     = fmaf(lo, lo, q[2 * k]);
      s[2 * k + 1] += hi; q[2 * k + 1] = fmaf(hi, hi, q[2 * k + 1]);
    }
  }
#pragma unroll
  for (int k = 0; k < 8; ++k) { ls[t][k] = s[k]; lq[t][k] = q[k]; }
  __syncthreads();
  if (rg == 0) {
    float* slot = sums + (size_t)(blockIdx.x & (NSLOT - 1)) * 2 * D;
#pragma unroll
    for (int g = 1; g < 8; ++g)
#pragma unroll
      for (int k = 0; k < 8; ++k) { s[k] += ls[cg + 32 * g][k]; q[k] += lq[cg + 32 * g][k]; }
#pragma unroll
    for (int k = 0; k < 8; ++k) {
      atomicAdd(&slot[cg * 8 + k], s[k]);
      atomicAdd(&slot[D + cg * 8 + k], q[k]);
    }
  }
}

// ---------------- Classifier (BN folded in; sums = 8-slot base) -------------
__global__ void k_classifier(const unsigned short* __restrict__ F, const float* __restrict__ W,
                             const float* __restrict__ sums, const float* __restrict__ cls_b,
                             float* __restrict__ out, int N, int baseRow, int initMode)
{
  __shared__ float smu[D], srs[D];
  const int t = threadIdx.x;
  {
    float sAcc = 0.f, qAcc = 0.f;
#pragma unroll
    for (int s8 = 0; s8 < NSLOT; ++s8) {
      sAcc += sums[s8 * 2 * D + t];
      qAcc += sums[s8 * 2 * D + D + t];
    }
    const float inv = 1.f / (float)N;
    const float m_ = sAcc * inv;
    smu[t] = m_;
    srs[t] = rsqrtf(qAcc * inv - m_ * m_ + BN_EPS);
  }
  __syncthreads();

  const int n = blockIdx.x * 8 + (t >> 5);
  if (n >= N) return;
  const int lane = t & 31;
  const uint4 f = *(const uint4*)(F + (size_t)n * D + lane * 8);
  const unsigned w[4] = {f.x, f.y, f.z, f.w};
  float fv[8];
#pragma unroll
  for (int k = 0; k < 4; ++k) {
    fv[2 * k]     = (bf2f((unsigned short)(w[k] & 0xffff)) - smu[lane * 8 + 2 * k])     * srs[lane * 8 + 2 * k];
    fv[2 * k + 1] = (bf2f((unsigned short)(w[k] >> 16))    - smu[lane * 8 + 2 * k + 1]) * srs[lane * 8 + 2 * k + 1];
  }
  const float* Wr = W + (size_t)(baseRow + lane * 8) * NCLS;
  float p[NCLS];
#pragma unroll
  for (int c = 0; c < NCLS; ++c) {
    float s = 0.f;
#pragma unroll
    for (int k = 0; k < 8; ++k) s = fmaf(fv[k], Wr[k * NCLS + c], s);
    p[c] = s;
  }
#pragma unroll
  for (int m = 1; m < 32; m <<= 1)
#pragma unroll
    for (int c = 0; c < NCLS; ++c) p[c] += __shfl_xor(p[c], m);
  if (lane == 0) {
    float* o = out + (size_t)n * NCLS;
    if (initMode) {
#pragma unroll
      for (int c = 0; c < NCLS; ++c) o[c] = p[c] + cls_b[c];
    } else {
#pragma unroll
      for (int c = 0; c < NCLS; ++c) o[c] += p[c];
    }
  }
}

// ---------------------------------------------------------------------------
extern "C" void kernel_launch(void* const* d_in, const int* in_sizes, int n_in,
                              void* d_out, int out_size, void* d_ws, size_t ws_size,
                              hipStream_t stream)
{
  const float* f_in   = (const float*)d_in[0];
  const int*   erow   = (const int*)d_in[1];
  const int*   ecol   = (const int*)d_in[2];
  const float* eval   = (const float*)d_in[3];
  const float* gat_Ws = (const float*)d_in[4];
  const float* gat_bs = (const float*)d_in[5];
  const float* gat_Wn = (const float*)d_in[6];
  const float* gat_bn = (const float*)d_in[7];
  const float* gat_as = (const float*)d_in[8];
  const float* gat_an = (const float*)d_in[9];
  const float* gcn_W  = (const float*)d_in[10];
  const float* gcn_b  = (const float*)d_in[11];
  const float* self_W = (const float*)d_in[12];
  const float* self_b = (const float*)d_in[13];
  const float* cls_W  = (const float*)d_in[14];
  const float* cls_b  = (const float*)d_in[15];
  float* out = (float*)d_out;

  const int N  = in_sizes[0] / D;      // 50000
  const int E  = in_sizes[1] / 4;      // 400000
  const int E4 = 4 * E, N4 = 4 * N;
  const size_t ND = (size_t)N * D;

  // ---- workspace carve-up (byte-identical footprint to round 3) ----
  unsigned short* bufA = (unsigned short*)d_ws;
  unsigned short* bufB = bufA + ND;
  unsigned short* bufC = bufB + ND;
  unsigned short* finB = bufC + ND;
  unsigned short* Wt   = finB + ND;                 // 11*65536
  float* attS   = (float*)(Wt + (size_t)11 * D * D);
  float* attN   = attS + (size_t)N * NHEAD;
  int*   scanTmp= (int*)(attN + (size_t)N * NHEAD);
  int*   blkSum = scanTmp + N4;
  int*   rowptr = blkSum + 1024;
  int2*  edge   = (int2*)(rowptr + (N4 + 4));
  // zeroed region: cnt[4N] | fill[4N]
  int*   cnt    = (int*)(edge + E4);
  int*   fill   = cnt + N4;
  // aliased into scanTmp (dead after CSR build; N4*4B = 800KB available):
  //   foldB: 5*256 f32 (5KB) | slotted bn sums: 9 * NSLOT * 2*D f32 (147KB)
  float* foldB    = (float*)scanTmp;
  float* slotSums = (float*)scanTmp + 2048;
  const size_t zero_bytes = (size_t)(2 * N4) * sizeof(int);
  const size_t slot_bytes = (size_t)9 * NSLOT * 2 * D * sizeof(float);

  const dim3 gemm_grid((N + 127) / 128, D / 128);
  const dim3 gemm_grid2((N + 127) / 128, 4);    // merged GAT: 512 cols
  const dim3 cvtw_grid(11, 8, 8);
  const int nb8   = (N + 7) / 8;
  const int nb4   = (N + 3) / 4;       // agg: 1 node/wave, 4 waves/block
  const int scanG = (N4 + 255) / 256;

  hipMemsetAsync(cnt, 0, zero_bytes, stream);

  // conversions
  k_cvt  <<<(int)(ND / 8 + 255) / 256, 256, 0, stream>>>(f_in, finB, (int)(ND / 8));
  k_cvt_w<<<cvtw_grid, 256, 0, stream>>>(gat_Ws, gat_Wn, gcn_W, self_W, Wt);

  // batched CSR for 4 adjacencies
  k_count   <<<(E4 + 255) / 256, 256, 0, stream>>>(erow, cnt, E4, E, N);
  k_scan_blk<<<scanG, 256, 0, stream>>>(cnt, scanTmp, blkSum, N4);
  k_scan_top<<<1, 1024, 0, stream>>>(blkSum, scanG);
  k_scan_fin<<<scanG, 256, 0, stream>>>(scanTmp, blkSum, rowptr, N4);
  k_scatter <<<(E4 + 255) / 256, 256, 0, stream>>>(erow, ecol, eval, rowptr, fill,
                                                   edge, E4, E, N);

  // scanTmp is dead now — zero the aliased slot-sums region
  hipMemsetAsync(slotSums, 0, slot_bytes, stream);

  const size_t WM = (size_t)D * D;
  auto sumsOf = [&](int id) { return slotSums + (size_t)id * NSLOT * 2 * D; };
  auto stats = [&](unsigned short* X, int id) {
    k_bn_stats<<<256, 256, 0, stream>>>(X, sumsOf(id), N);
  };

  // ===================== GAT branch (adjacency 0) ==========================
  {
    const int* rp = rowptr;
    // layer 0: MERGED GEMM — slab0 = Ws(att only), slab1 = Wn -> bufB
    k_gemm_mfma<<<gemm_grid2, 256, 0, stream>>>(finB, Wt + 0 * WM, gat_bs, gat_bn,
                                                bufB, N, 1,
                                                gat_as, gat_an, attS, attN, nullptr);
    k_gat_agg  <<<nb4, 256, 0, stream>>>(bufB, attS, attN, rp, edge, bufC, N);
    stats(bufC, 0);
    // fold BN(0) into layer-1 weights (both Ws and Wn consume bufC)
    k_fold_w<<<D, 256, 0, stream>>>(gat_Ws + (size_t)NHEAD * D * 32, gat_bs + D,
                                    sumsOf(0), Wt + 2 * WM, foldB + 0 * D, 0, N);
    k_fold_w<<<D, 256, 0, stream>>>(gat_Wn + (size_t)NHEAD * D * 32, gat_bn + D,
                                    sumsOf(0), Wt + 3 * WM, foldB + 1 * D, 0, N);
    // layer 1: MERGED GEMM — slab0 = Ws'(att only), slab1 = Wn' -> bufB
    k_gemm_mfma<<<gemm_grid2, 256, 0, stream>>>(bufC, Wt + 2 * WM, foldB + 0 * D,
                                                foldB + 1 * D, bufB, N, 1,
                                                gat_as + D, gat_an + D, attS, attN, nullptr);
    k_gat_agg  <<<nb4, 256, 0, stream>>>(bufB, attS, attN, rp, edge, bufA, N);
    stats(bufA, 1);
    k_classifier<<<nb8, 256, 0, stream>>>(bufA, cls_W, sumsOf(1), cls_b, out, N, 0, 1);
  }

  // ===================== 3 GCN branches (adjacency 1..3) ===================
  for (int g = 0; g < 3; ++g) {
    const int* rp = rowptr + (size_t)(g + 1) * N;
    const float* bg = gcn_b + (size_t)g * 2 * D;
    k_gemm_mfma<<<gemm_grid, 256, 0, stream>>>(finB, Wt + (4 + 2 * g) * WM, bg, bg,
                                               bufA, N, 0,
                                               nullptr, nullptr, nullptr, nullptr, nullptr);
    k_gcn_agg  <<<nb4, 256, 0, stream>>>(bufA, rp, edge, bufB, N);
    stats(bufB, 2 + 2 * g);
    // fold BN(2+2g) into layer-2 weights
    k_fold_w<<<D, 256, 0, stream>>>(gcn_W + (size_t)(2 * g + 1) * D * D, bg + D,
                                    sumsOf(2 + 2 * g),
                                    Wt + (5 + 2 * g) * WM, foldB + (2 + g) * D, 1, N);
    k_gemm_mfma<<<gemm_grid, 256, 0, stream>>>(bufB, Wt + (5 + 2 * g) * WM,
                                               foldB + (2 + g) * D, foldB + (2 + g) * D,
                                               bufA, N, 0,
                                               nullptr, nullptr, nullptr, nullptr, nullptr);
    k_gcn_agg  <<<nb4, 256, 0, stream>>>(bufA, rp, edge, bufB, N);
    stats(bufB, 3 + 2 * g);
    k_classifier<<<nb8, 256, 0, stream>>>(bufB, cls_W, sumsOf(3 + 2 * g), cls_b,
                                          out, N, (1 + g) * D, 0);
  }

  // ===================== self perceptron (stats fused, slot-replicated) ====
  k_gemm_mfma<<<gemm_grid, 256, 0, stream>>>(finB, Wt + 10 * WM, self_b, self_b,
                                             bufA, N, 1,
                                             nullptr, nullptr, nullptr, nullptr,
                                             sumsOf(8));
  k_classifier<<<nb8, 256, 0, stream>>>(bufA, cls_W, sumsOf(8), cls_b, out, N, 4 * D, 0);
}

// Round 13
// 1161.706 us; speedup vs baseline: 2.3156x; 1.0081x over previous
//
#include <hip/hip_runtime.h>

// ---------------------------------------------------------------------------
// ERC GNN forward — round 16 (r15 + ONE change: GEMM LDS swizzle):
//  * r15 counters: GEMM top dispatch, MfmaUtil 5.8%, 1.6M LDS bank-conflict
//    cycles. Fragment read As[row*32+quad*8] puts 16 lanes on 2 four-bank
//    groups = 8-way conflict (2.94x serialization, m136).
//  * FIX (both-sides-or-neither, rule 21): linear gload_lds dest +
//    inverse-permuted GLOBAL source k-chunk (c = (l&3 - l>>3)&3) +
//    permuted ds_read slot ((quad + (l16>>1))&3). 2-way spread = free.
//    Data delivered to MFMA is bit-identical.
//  * Everything else identical to r15 (1171 µs).
// ---------------------------------------------------------------------------

constexpr int D     = 256;
constexpr int NHEAD = 8;
constexpr int NCLS  = 7;
constexpr int NSLOT = 8;                    // bn-stats slot replication
constexpr float BN_EPS = 1e-9f;

typedef short  s16x8 __attribute__((ext_vector_type(8)));
typedef float  f32x4 __attribute__((ext_vector_type(4)));

__device__ __forceinline__ unsigned short f2bf(float f) {
  unsigned int u = __builtin_bit_cast(unsigned int, f);
  u += 0x7FFFu + ((u >> 16) & 1u);          // round-to-nearest-even
  return (unsigned short)(u >> 16);
}
__device__ __forceinline__ float bf2f(unsigned short h) {
  unsigned int u = ((unsigned int)h) << 16;
  return __builtin_bit_cast(float, u);
}

__device__ __forceinline__ void gload_lds16(const void* g, void* l) {
  __builtin_amdgcn_global_load_lds(
      (const __attribute__((address_space(1))) unsigned int*)g,
      (__attribute__((address_space(3))) unsigned int*)l, 16, 0, 0);
}

// ---------------- bf16 MFMA GEMM: C[M,cols] = A[M,256] @ Wt^T + bias --------
// Merged-GAT mode (attS!=null, grid.y=4 over 512 cols):
//   cols [0,256): att epilogue only; cols [256,512): relu path, bias=biasB.
// Normal mode: optional slot-replicated BN stats epilogue (bnOut).
// LDS swizzle: LDS[R][slot] holds global k-chunk (slot - (R>>1))&3.
//   store side: linear dest, source chunk c = ((l&3) - ((l>>3)&3))&3;
//   read side:  chunk q lives at slot (q + (R>>1))&3 = (quad + (l16>>1))&3
//   (wm/wn/mi*16 are =0 mod 8 after >>1, so slot is per-thread constant).
__launch_bounds__(256)
__global__ void k_gemm_mfma(const unsigned short* __restrict__ A,
                            const unsigned short* __restrict__ Wt,
                            const float* __restrict__ bias,
                            const float* __restrict__ biasB,
                            unsigned short* __restrict__ C,
                            int M, int doRelu,
                            const float* __restrict__ a_s, const float* __restrict__ a_n,
                            float* __restrict__ attS, float* __restrict__ attN,
                            float* __restrict__ bnOut)
{
  __shared__ unsigned short As[128 * 32];
  __shared__ unsigned short Bs[128 * 32];
  const int t = threadIdx.x;
  const int wave = t >> 6, lane = t & 63;
  const int quad = lane >> 4, l16 = lane & 15;
  const int wm = (wave & 1) * 64, wn = (wave >> 1) * 64;
  const int bm = blockIdx.x * 128, bn = blockIdx.y * 128;

  f32x4 acc[4][4] = {};

  const int rA0 = wave * 32 + (lane >> 2);
  const int rA1 = rA0 + 16;
  // swizzled global k-chunk for this lane's linear LDS slot (lane&3):
  const int sub = (((lane & 3) - ((lane >> 3) & 3)) & 3) * 8;
  const unsigned short* gA0 = A  + (size_t)min(bm + rA0, M - 1) * D + sub;
  const unsigned short* gA1 = A  + (size_t)min(bm + rA1, M - 1) * D + sub;
  const unsigned short* gB0 = Wt + (size_t)(bn + rA0) * D + sub;
  const unsigned short* gB1 = Wt + (size_t)(bn + rA1) * D + sub;
  unsigned short* lA0 = &As[wave * 1024];
  unsigned short* lA1 = &As[wave * 1024 + 512];
  unsigned short* lB0 = &Bs[wave * 1024];
  unsigned short* lB1 = &Bs[wave * 1024 + 512];

  // swizzled ds_read slot offset (replaces quad*8); per-thread constant
  const int roff = ((quad + (l16 >> 1)) & 3) * 8;

  for (int k0 = 0; k0 < D; k0 += 32) {
    gload_lds16(gA0 + k0, lA0);
    gload_lds16(gA1 + k0, lA1);
    gload_lds16(gB0 + k0, lB0);
    gload_lds16(gB1 + k0, lB1);
    __syncthreads();
    s16x8 af[4], bf[4];
#pragma unroll
    for (int mi = 0; mi < 4; ++mi)
      af[mi] = *(const s16x8*)(&As[(wm + mi * 16 + l16) * 32 + roff]);
#pragma unroll
    for (int nj = 0; nj < 4; ++nj)
      bf[nj] = *(const s16x8*)(&Bs[(wn + nj * 16 + l16) * 32 + roff]);
#pragma unroll
    for (int mi = 0; mi < 4; ++mi)
#pragma unroll
      for (int nj = 0; nj < 4; ++nj)
        acc[mi][nj] = __builtin_amdgcn_mfma_f32_16x16x32_bf16(af[mi], bf[nj], acc[mi][nj], 0, 0, 0);
    __syncthreads();
  }

  // C/D layout: col = l16, row = quad*4 + reg (m89-verified)
  const bool attSlab = (attS != nullptr) && (bn < 256);
  if (attSlab) {
    const int hb = (bn + wn) >> 5;
#pragma unroll
    for (int mi = 0; mi < 4; ++mi) {
#pragma unroll
      for (int h = 0; h < 2; ++h) {
        float ps[4] = {}, pn[4] = {};
#pragma unroll
        for (int j = 0; j < 2; ++j) {
          const int nj = h * 2 + j;
          const int col = bn + wn + nj * 16 + l16;
          const float bv = bias[col];
          const float av = a_s[col], nv = a_n[col];
#pragma unroll
          for (int r = 0; r < 4; ++r) {
            const float v = fmaxf(acc[mi][nj][r] + bv, 0.f);
            ps[r] = fmaf(v, av, ps[r]);
            pn[r] = fmaf(v, nv, pn[r]);
          }
        }
#pragma unroll
        for (int m = 1; m < 16; m <<= 1)
#pragma unroll
          for (int r = 0; r < 4; ++r) {
            ps[r] += __shfl_xor(ps[r], m);
            pn[r] += __shfl_xor(pn[r], m);
          }
        if (l16 == 0) {
#pragma unroll
          for (int r = 0; r < 4; ++r) {
            const int row = bm + wm + mi * 16 + quad * 4 + r;
            if (row < M) {
              const float s_ = ps[r], n_ = pn[r];
              attS[(size_t)row * NHEAD + hb + h] = (s_ > 0.f) ? s_ : 0.2f * s_;
              attN[(size_t)row * NHEAD + hb + h] = (n_ > 0.f) ? n_ : 0.2f * n_;
            }
          }
        }
      }
    }
  } else {
    // normal path; in merged-GAT mode this is the Wn slab (cols 256..511)
    const int cBase = (attS != nullptr) ? 256 : 0;
    const float* bsrc = (attS != nullptr) ? biasB : bias;
    float cs[4] = {}, cq[4] = {};
#pragma unroll
    for (int nj = 0; nj < 4; ++nj) {
      const int col = bn + wn + nj * 16 + l16;       // Wt row index
      const int cw  = col - cBase;                   // output col
      const float bv = bsrc[cw];
#pragma unroll
      for (int mi = 0; mi < 4; ++mi) {
#pragma unroll
        for (int r = 0; r < 4; ++r) {
          const int row = bm + wm + mi * 16 + quad * 4 + r;
          if (row < M) {
            float v = acc[mi][nj][r] + bv;
            if (doRelu) v = fmaxf(v, 0.f);
            const unsigned short u = f2bf(v);
            C[(size_t)row * D + cw] = u;
            if (bnOut) {
              const float w = bf2f(u);
              cs[nj] += w;
              cq[nj] = fmaf(w, w, cq[nj]);
            }
          }
        }
      }
    }
    if (bnOut) {
      // quad-reduce (lanes l16,+16,+32,+48 share a column), slot-replicated
#pragma unroll
      for (int nj = 0; nj < 4; ++nj) {
        cs[nj] += __shfl_xor(cs[nj], 16);
        cq[nj] += __shfl_xor(cq[nj], 16);
        cs[nj] += __shfl_xor(cs[nj], 32);
        cq[nj] += __shfl_xor(cq[nj], 32);
      }
      if (quad == 0) {
        float* slot = bnOut + (size_t)(blockIdx.x & (NSLOT - 1)) * 2 * D;
#pragma unroll
        for (int nj = 0; nj < 4; ++nj) {
          const int col = bn + wn + nj * 16 + l16;
          atomicAdd(&slot[col], cs[nj]);
          atomicAdd(&slot[D + col], cq[nj]);
        }
      }
    }
  }
}

// ---------------- conversions -----------------------------------------------
__global__ void k_cvt(const float* __restrict__ src, unsigned short* __restrict__ dst, int n8)
{
  const int i = blockIdx.x * 256 + threadIdx.x;
  if (i >= n8) return;
  const float4 a = *(const float4*)(src + (size_t)i * 8);
  const float4 b = *(const float4*)(src + (size_t)i * 8 + 4);
  uint4 o;
  o.x = (unsigned)f2bf(a.x) | ((unsigned)f2bf(a.y) << 16);
  o.y = (unsigned)f2bf(a.z) | ((unsigned)f2bf(a.w) << 16);
  o.z = (unsigned)f2bf(b.x) | ((unsigned)f2bf(b.y) << 16);
  o.w = (unsigned)f2bf(b.z) | ((unsigned)f2bf(b.w) << 16);
  *(uint4*)(dst + (size_t)i * 8) = o;
}

// LDS tile-transposed weight conversion: reads and writes both coalesced.
// grid = (11 m-slabs, 8 j-tiles, 8 d-tiles), block = 256.
__global__ void k_cvt_w(const float* __restrict__ gat_Ws, const float* __restrict__ gat_Wn,
                        const float* __restrict__ gcn_W, const float* __restrict__ self_W,
                        unsigned short* __restrict__ Wt)
{
  __shared__ float tile[32][33];
  const int m = blockIdx.x, jt = blockIdx.y, dt = blockIdx.z;
  const int tx = threadIdx.x & 31, ty = threadIdx.x >> 5;
#pragma unroll
  for (int r = 0; r < 4; ++r) {
    const int dl = ty * 4 + r;                 // d_local
    const int d  = dt * 32 + dl;
    float v;
    if (m < 4) {
      const int l = m >> 1;
      const float* W = (m & 1) ? gat_Wn : gat_Ws;           // [L,H,D,DH]
      v = W[(((size_t)l * NHEAD + jt) * D + d) * 32 + tx];  // j>>5=jt, j&31=tx
    } else if (m < 10) {
      v = gcn_W[((size_t)(m - 4) * D + d) * D + jt * 32 + tx];
    } else {
      v = self_W[(size_t)d * D + jt * 32 + tx];
    }
    tile[dl][tx] = v;                          // [d_local][j_local]
  }
  __syncthreads();
#pragma unroll
  for (int r = 0; r < 4; ++r) {
    const int jl = ty * 4 + r;                 // j_local
    const int j  = jt * 32 + jl;
    const int d  = dt * 32 + tx;
    Wt[((size_t)m * D + j) * D + d] = f2bf(tile[tx][jl]);
  }
}

// ---------------- BN-fold: W'[j,d] = rs_d*W[j,d]; b'[j] = b[j]-Σ mu_d*W'[j,d]
// sums = 8-slot base. mode 0: GAT layout [H,D,DH]; mode 1: GCN [D_in,D_out]
__global__ void k_fold_w(const float* __restrict__ srcW, const float* __restrict__ srcB,
                         const float* __restrict__ sums, unsigned short* __restrict__ dstW,
                         float* __restrict__ dstB, int mode, int Nn)
{
  __shared__ float red[256];
  const int j = blockIdx.x;      // out col
  const int d = threadIdx.x;     // in dim (BN axis)
  float sAcc = 0.f, qAcc = 0.f;
#pragma unroll
  for (int s8 = 0; s8 < NSLOT; ++s8) {
    sAcc += sums[s8 * 2 * D + d];
    qAcc += sums[s8 * 2 * D + D + d];
  }
  const float inv = 1.f / (float)Nn;
  const float m_ = sAcc * inv;
  const float rs = rsqrtf(qAcc * inv - m_ * m_ + BN_EPS);
  float w;
  if (mode == 0) w = srcW[(((size_t)(j >> 5)) * D + d) * 32 + (j & 31)];
  else           w = srcW[(size_t)d * D + j];
  const unsigned short q = f2bf(w * rs);
  dstW[(size_t)j * D + d] = q;
  red[d] = m_ * bf2f(q);         // use quantized weight so fold is exact vs GEMM
  __syncthreads();
  for (int off = 128; off > 0; off >>= 1) {
    if (d < off) red[d] += red[d + off];
    __syncthreads();
  }
  if (d == 0) dstB[j] = srcB[j] - red[0];
}

// ---------------- batched CSR build (4 adjacencies) --------------------------
__global__ void k_count(const int* __restrict__ rows, int* __restrict__ cnt, int E4, int E, int N)
{
  const int i = blockIdx.x * 256 + threadIdx.x;
  if (i < E4) atomicAdd(&cnt[(i / E) * N + rows[i]], 1);
}

__global__ void k_scan_blk(const int* __restrict__ in, int* __restrict__ scanTmp,
                           int* __restrict__ blkSum, int n)
{
  __shared__ int buf[256];
  const int t = threadIdx.x, i = blockIdx.x * 256 + t;
  const int v = (i < n) ? in[i] : 0;
  buf[t] = v; __syncthreads();
  for (int off = 1; off < 256; off <<= 1) {
    const int x = (t >= off) ? buf[t - off] : 0;
    __syncthreads();
    buf[t] += x; __syncthreads();
  }
  if (i < n) scanTmp[i] = buf[t];
  if (t == 255) blkSum[blockIdx.x] = buf[255];
}

__global__ void k_scan_top(int* __restrict__ blkSum, int G)
{
  __shared__ int buf[1024];
  const int t = threadIdx.x;
  const int v = (t < G) ? blkSum[t] : 0;
  buf[t] = v; __syncthreads();
  for (int off = 1; off < 1024; off <<= 1) {
    const int x = (t >= off) ? buf[t - off] : 0;
    __syncthreads();
    buf[t] += x; __syncthreads();
  }
  if (t < G) blkSum[t] = buf[t] - v;
}

__global__ void k_scan_fin(const int* __restrict__ scanTmp, const int* __restrict__ blkOff,
                           int* __restrict__ rowptr, int n)
{
  const int i = blockIdx.x * 256 + threadIdx.x;
  if (i < n) rowptr[i + 1] = scanTmp[i] + blkOff[blockIdx.x];
  if (i == 0) rowptr[0] = 0;
}

// packed scatter: one 8B store per edge {col, val-bits}
__global__ void k_scatter(const int* __restrict__ rows, const int* __restrict__ cols,
                          const float* __restrict__ vals,
                          const int* __restrict__ rowptr, int* __restrict__ fill,
                          int2* __restrict__ edge, int E4, int E, int N)
{
  const int i = blockIdx.x * 256 + threadIdx.x;
  if (i >= E4) return;
  const int g = (i / E) * N + rows[i];
  const int p = rowptr[g] + atomicAdd(&fill[g], 1);
  edge[p] = make_int2(cols[i], __float_as_int(vals[i]));
}

// ---------------- Aggregations: 1 node/WAVE, half-waves split edge pairs ----
__device__ __forceinline__ void acc8(float* a, uint4 f, float c) {
  const unsigned w[4] = {f.x, f.y, f.z, f.w};
#pragma unroll
  for (int k = 0; k < 4; ++k) {
    a[2 * k]     = fmaf(c, bf2f((unsigned short)(w[k] & 0xffff)), a[2 * k]);
    a[2 * k + 1] = fmaf(c, bf2f((unsigned short)(w[k] >> 16)),    a[2 * k + 1]);
  }
}

__device__ __forceinline__ uint4 pack8(const float* a, bool relu) {
  unsigned ov[4];
#pragma unroll
  for (int k = 0; k < 4; ++k) {
    float lo = a[2 * k], hi = a[2 * k + 1];
    if (relu) { lo = fmaxf(lo, 0.f); hi = fmaxf(hi, 0.f); }
    ov[k] = (unsigned)f2bf(lo) | ((unsigned)f2bf(hi) << 16);
  }
  uint4 o; o.x = ov[0]; o.y = ov[1]; o.z = ov[2]; o.w = ov[3];
  return o;
}

__global__ void k_gat_agg(const unsigned short* __restrict__ fneigh,
                          const float* __restrict__ attS, const float* __restrict__ attN,
                          const int* __restrict__ rowptr, const int2* __restrict__ edge,
                          unsigned short* __restrict__ out, int N)
{
  const int n = blockIdx.x * 4 + (threadIdx.x >> 6);
  if (n >= N) return;                         // wave-uniform (n per wave)
  const int lane = threadIdx.x & 63;
  const int half = lane >> 5;                 // which edge of the pair
  const int c32  = lane & 31;                 // 8 cols/lane
  const int head = c32 >> 2;                  // 32 cols/head
  const float as = attS[(size_t)n * NHEAD + head];
  float a[8] = {};
  int p = rowptr[n];
  const int e = rowptr[n + 1];
  for (; p + 3 < e; p += 4) {                 // 4 edges / iter (2 pairs)
    const int2 ea = edge[p + half];
    const int2 eb = edge[p + 2 + half];
    const float ca = (as + attN[(size_t)ea.x * NHEAD + head]) * __int_as_float(ea.y);
    const float cb = (as + attN[(size_t)eb.x * NHEAD + head]) * __int_as_float(eb.y);
    const uint4 fa = *(const uint4*)(fneigh + (size_t)ea.x * D + c32 * 8);
    const uint4 fb = *(const uint4*)(fneigh + (size_t)eb.x * D + c32 * 8);
    acc8(a, fa, ca);
    acc8(a, fb, cb);
  }
  if (p + 1 < e) {                            // one full pair
    const int2 ea = edge[p + half];
    const float ca = (as + attN[(size_t)ea.x * NHEAD + head]) * __int_as_float(ea.y);
    const uint4 fa = *(const uint4*)(fneigh + (size_t)ea.x * D + c32 * 8);
    acc8(a, fa, ca);
    p += 2;
  }
  if (p < e && half == 0) {                   // last single edge: lower half
    const int2 ea = edge[p];
    const float ca = (as + attN[(size_t)ea.x * NHEAD + head]) * __int_as_float(ea.y);
    const uint4 fa = *(const uint4*)(fneigh + (size_t)ea.x * D + c32 * 8);
    acc8(a, fa, ca);
  }
#pragma unroll
  for (int k = 0; k < 8; ++k) a[k] += __shfl_xor(a[k], 32);
  if (half == 0)
    *(uint4*)(out + (size_t)n * D + c32 * 8) = pack8(a, false);
}

__global__ void k_gcn_agg(const unsigned short* __restrict__ Hm,
                          const int* __restrict__ rowptr, const int2* __restrict__ edge,
                          unsigned short* __restrict__ out, int N)
{
  const int n = blockIdx.x * 4 + (threadIdx.x >> 6);
  if (n >= N) return;                         // wave-uniform (n per wave)
  const int lane = threadIdx.x & 63;
  const int half = lane >> 5;
  const int c32  = lane & 31;
  float a[8] = {};
  int p = rowptr[n];
  const int e = rowptr[n + 1];
  for (; p + 3 < e; p += 4) {                 // 4 edges / iter (2 pairs)
    const int2 ea = edge[p + half];
    const int2 eb = edge[p + 2 + half];
    const uint4 fa = *(const uint4*)(Hm + (size_t)ea.x * D + c32 * 8);
    const uint4 fb = *(const uint4*)(Hm + (size_t)eb.x * D + c32 * 8);
    acc8(a, fa, __int_as_float(ea.y));
    acc8(a, fb, __int_as_float(eb.y));
  }
  if (p + 1 < e) {                            // one full pair
    const int2 ea = edge[p + half];
    const uint4 fa = *(const uint4*)(Hm + (size_t)ea.x * D + c32 * 8);
    acc8(a, fa, __int_as_float(ea.y));
    p += 2;
  }
  if (p < e && half == 0) {                   // last single edge: lower half
    const int2 ea = edge[p];
    const uint4 fa = *(const uint4*)(Hm + (size_t)ea.x * D + c32 * 8);
    acc8(a, fa, __int_as_float(ea.y));
  }
#pragma unroll
  for (int k = 0; k < 8; ++k) a[k] += __shfl_xor(a[k], 32);
  if (half == 0)
    *(uint4*)(out + (size_t)n * D + c32 * 8) = pack8(a, true);  // relu pre-BN
}

// ---------------- BatchNorm stats: 8-slot replicated sums -------------------
// 256 blocks; block b atomics into slot (b & 7) -> 32 contributors/address.
__launch_bounds__(256)
__global__ void k_bn_stats(const unsigned short* __restrict__ X, float* __restrict__ sums, int M)
{
  __shared__ float ls[256][8];
  __shared__ float lq[256][8];
  const int t = threadIdx.x, cg = t & 31, rg = t >> 5;
  float s[8] = {}, q[8] = {};
  for (int r = blockIdx.x * 8 + rg; r < M; r += gridDim.x * 8) {
    const uint4 f = *(const uint4*)(X + (size_t)r * D + cg * 8);
    const unsigned w[4] = {f.x, f.y, f.z, f.w};
#pragma unroll
    for (int k = 0; k < 4; ++k) {
      const float lo = bf2f((unsigned short)(w[k] & 0xffff));
      const float hi = bf2f((unsigned short)(w[k] >> 16));
      s[2 * k]     += lo; q[2 * k]     = fmaf(lo, lo, q[2 * k]);
      s[2 * k + 1] += hi; q[2 * k + 1] = fmaf(hi, hi, q[2 * k + 1]);
    }
  }
#pragma unroll
  for (int k = 0; k < 8; ++k) { ls[t][k] = s[k]; lq[t][k] = q[k]; }
  __syncthreads();
  if (rg == 0) {
    float* slot = sums + (size_t)(blockIdx.x & (NSLOT - 1)) * 2 * D;
#pragma unroll
    for (int g = 1; g < 8; ++g)
#pragma unroll
      for (int k = 0; k < 8; ++k) { s[k] += ls[cg + 32 * g][k]; q[k] += lq[cg + 32 * g][k]; }
#pragma unroll
    for (int k = 0; k < 8; ++k) {
      atomicAdd(&slot[cg * 8 + k], s[k]);
      atomicAdd(&slot[D + cg * 8 + k], q[k]);
    }
  }
}

// ---------------- Classifier (BN folded in; sums = 8-slot base) -------------
__global__ void k_classifier(const unsigned short* __restrict__ F, const float* __restrict__ W,
                             const float* __restrict__ sums, const float* __restrict__ cls_b,
                             float* __restrict__ out, int N, int baseRow, int initMode)
{
  __shared__ float smu[D], srs[D];
  const int t = threadIdx.x;
  {
    float sAcc = 0.f, qAcc = 0.f;
#pragma unroll
    for (int s8 = 0; s8 < NSLOT; ++s8) {
      sAcc += sums[s8 * 2 * D + t];
      qAcc += sums[s8 * 2 * D + D + t];
    }
    const float inv = 1.f / (float)N;
    const float m_ = sAcc * inv;
    smu[t] = m_;
    srs[t] = rsqrtf(qAcc * inv - m_ * m_ + BN_EPS);
  }
  __syncthreads();

  const int n = blockIdx.x * 8 + (t >> 5);
  if (n >= N) return;
  const int lane = t & 31;
  const uint4 f = *(const uint4*)(F + (size_t)n * D + lane * 8);
  const unsigned w[4] = {f.x, f.y, f.z, f.w};
  float fv[8];
#pragma unroll
  for (int k = 0; k < 4; ++k) {
    fv[2 * k]     = (bf2f((unsigned short)(w[k] & 0xffff)) - smu[lane * 8 + 2 * k])     * srs[lane * 8 + 2 * k];
    fv[2 * k + 1] = (bf2f((unsigned short)(w[k] >> 16))    - smu[lane * 8 + 2 * k + 1]) * srs[lane * 8 + 2 * k + 1];
  }
  const float* Wr = W + (size_t)(baseRow + lane * 8) * NCLS;
  float p[NCLS];
#pragma unroll
  for (int c = 0; c < NCLS; ++c) {
    float s = 0.f;
#pragma unroll
    for (int k = 0; k < 8; ++k) s = fmaf(fv[k], Wr[k * NCLS + c], s);
    p[c] = s;
  }
#pragma unroll
  for (int m = 1; m < 32; m <<= 1)
#pragma unroll
    for (int c = 0; c < NCLS; ++c) p[c] += __shfl_xor(p[c], m);
  if (lane == 0) {
    float* o = out + (size_t)n * NCLS;
    if (initMode) {
#pragma unroll
      for (int c = 0; c < NCLS; ++c) o[c] = p[c] + cls_b[c];
    } else {
#pragma unroll
      for (int c = 0; c < NCLS; ++c) o[c] += p[c];
    }
  }
}

// ---------------------------------------------------------------------------
extern "C" void kernel_launch(void* const* d_in, const int* in_sizes, int n_in,
                              void* d_out, int out_size, void* d_ws, size_t ws_size,
                              hipStream_t stream)
{
  const float* f_in   = (const float*)d_in[0];
  const int*   erow   = (const int*)d_in[1];
  const int*   ecol   = (const int*)d_in[2];
  const float* eval   = (const float*)d_in[3];
  const float* gat_Ws = (const float*)d_in[4];
  const float* gat_bs = (const float*)d_in[5];
  const float* gat_Wn = (const float*)d_in[6];
  const float* gat_bn = (const float*)d_in[7];
  const float* gat_as = (const float*)d_in[8];
  const float* gat_an = (const float*)d_in[9];
  const float* gcn_W  = (const float*)d_in[10];
  const float* gcn_b  = (const float*)d_in[11];
  const float* self_W = (const float*)d_in[12];
  const float* self_b = (const float*)d_in[13];
  const float* cls_W  = (const float*)d_in[14];
  const float* cls_b  = (const float*)d_in[15];
  float* out = (float*)d_out;

  const int N  = in_sizes[0] / D;      // 50000
  const int E  = in_sizes[1] / 4;      // 400000
  const int E4 = 4 * E, N4 = 4 * N;
  const size_t ND = (size_t)N * D;

  // ---- workspace carve-up (byte-identical footprint to round 3) ----
  unsigned short* bufA = (unsigned short*)d_ws;
  unsigned short* bufB = bufA + ND;
  unsigned short* bufC = bufB + ND;
  unsigned short* finB = bufC + ND;
  unsigned short* Wt   = finB + ND;                 // 11*65536
  float* attS   = (float*)(Wt + (size_t)11 * D * D);
  float* attN   = attS + (size_t)N * NHEAD;
  int*   scanTmp= (int*)(attN + (size_t)N * NHEAD);
  int*   blkSum = scanTmp + N4;
  int*   rowptr = blkSum + 1024;
  int2*  edge   = (int2*)(rowptr + (N4 + 4));
  // zeroed region: cnt[4N] | fill[4N]
  int*   cnt    = (int*)(edge + E4);
  int*   fill   = cnt + N4;
  // aliased into scanTmp (dead after CSR build; N4*4B = 800KB available):
  //   foldB: 5*256 f32 (5KB) | slotted bn sums: 9 * NSLOT * 2*D f32 (147KB)
  float* foldB    = (float*)scanTmp;
  float* slotSums = (float*)scanTmp + 2048;
  const size_t zero_bytes = (size_t)(2 * N4) * sizeof(int);
  const size_t slot_bytes = (size_t)9 * NSLOT * 2 * D * sizeof(float);

  const dim3 gemm_grid((N + 127) / 128, D / 128);
  const dim3 gemm_grid2((N + 127) / 128, 4);    // merged GAT: 512 cols
  const dim3 cvtw_grid(11, 8, 8);
  const int nb8   = (N + 7) / 8;
  const int nb4   = (N + 3) / 4;       // agg: 1 node/wave, 4 waves/block
  const int scanG = (N4 + 255) / 256;

  hipMemsetAsync(cnt, 0, zero_bytes, stream);

  // conversions
  k_cvt  <<<(int)(ND / 8 + 255) / 256, 256, 0, stream>>>(f_in, finB, (int)(ND / 8));
  k_cvt_w<<<cvtw_grid, 256, 0, stream>>>(gat_Ws, gat_Wn, gcn_W, self_W, Wt);

  // batched CSR for 4 adjacencies
  k_count   <<<(E4 + 255) / 256, 256, 0, stream>>>(erow, cnt, E4, E, N);
  k_scan_blk<<<scanG, 256, 0, stream>>>(cnt, scanTmp, blkSum, N4);
  k_scan_top<<<1, 1024, 0, stream>>>(blkSum, scanG);
  k_scan_fin<<<scanG, 256, 0, stream>>>(scanTmp, blkSum, rowptr, N4);
  k_scatter <<<(E4 + 255) / 256, 256, 0, stream>>>(erow, ecol, eval, rowptr, fill,
                                                   edge, E4, E, N);

  // scanTmp is dead now — zero the aliased slot-sums region
  hipMemsetAsync(slotSums, 0, slot_bytes, stream);

  const size_t WM = (size_t)D * D;
  auto sumsOf = [&](int id) { return slotSums + (size_t)id * NSLOT * 2 * D; };
  auto stats = [&](unsigned short* X, int id) {
    k_bn_stats<<<256, 256, 0, stream>>>(X, sumsOf(id), N);
  };

  // ===================== GAT branch (adjacency 0) ==========================
  {
    const int* rp = rowptr;
    // layer 0: MERGED GEMM — slab0 = Ws(att only), slab1 = Wn -> bufB
    k_gemm_mfma<<<gemm_grid2, 256, 0, stream>>>(finB, Wt + 0 * WM, gat_bs, gat_bn,
                                                bufB, N, 1,
                                                gat_as, gat_an, attS, attN, nullptr);
    k_gat_agg  <<<nb4, 256, 0, stream>>>(bufB, attS, attN, rp, edge, bufC, N);
    stats(bufC, 0);
    // fold BN(0) into layer-1 weights (both Ws and Wn consume bufC)
    k_fold_w<<<D, 256, 0, stream>>>(gat_Ws + (size_t)NHEAD * D * 32, gat_bs + D,
                                    sumsOf(0), Wt + 2 * WM, foldB + 0 * D, 0, N);
    k_fold_w<<<D, 256, 0, stream>>>(gat_Wn + (size_t)NHEAD * D * 32, gat_bn + D,
                                    sumsOf(0), Wt + 3 * WM, foldB + 1 * D, 0, N);
    // layer 1: MERGED GEMM — slab0 = Ws'(att only), slab1 = Wn' -> bufB
    k_gemm_mfma<<<gemm_grid2, 256, 0, stream>>>(bufC, Wt + 2 * WM, foldB + 0 * D,
                                                foldB + 1 * D, bufB, N, 1,
                                                gat_as + D, gat_an + D, attS, attN, nullptr);
    k_gat_agg  <<<nb4, 256, 0, stream>>>(bufB, attS, attN, rp, edge, bufA, N);
    stats(bufA, 1);
    k_classifier<<<nb8, 256, 0, stream>>>(bufA, cls_W, sumsOf(1), cls_b, out, N, 0, 1);
  }

  // ===================== 3 GCN branches (adjacency 1..3) ===================
  for (int g = 0; g < 3; ++g) {
    const int* rp = rowptr + (size_t)(g + 1) * N;
    const float* bg = gcn_b + (size_t)g * 2 * D;
    k_gemm_mfma<<<gemm_grid, 256, 0, stream>>>(finB, Wt + (4 + 2 * g) * WM, bg, bg,
                                               bufA, N, 0,
                                               nullptr, nullptr, nullptr, nullptr, nullptr);
    k_gcn_agg  <<<nb4, 256, 0, stream>>>(bufA, rp, edge, bufB, N);
    stats(bufB, 2 + 2 * g);
    // fold BN(2+2g) into layer-2 weights
    k_fold_w<<<D, 256, 0, stream>>>(gcn_W + (size_t)(2 * g + 1) * D * D, bg + D,
                                    sumsOf(2 + 2 * g),
                                    Wt + (5 + 2 * g) * WM, foldB + (2 + g) * D, 1, N);
    k_gemm_mfma<<<gemm_grid, 256, 0, stream>>>(bufB, Wt + (5 + 2 * g) * WM,
                                               foldB + (2 + g) * D, foldB + (2 + g) * D,
                                               bufA, N, 0,
                                               nullptr, nullptr, nullptr, nullptr, nullptr);
    k_gcn_agg  <<<nb4, 256, 0, stream>>>(bufA, rp, edge, bufB, N);
    stats(bufB, 3 + 2 * g);
    k_classifier<<<nb8, 256, 0, stream>>>(bufB, cls_W, sumsOf(3 + 2 * g), cls_b,
                                          out, N, (1 + g) * D, 0);
  }

  // ===================== self perceptron (stats fused, slot-replicated) ====
  k_gemm_mfma<<<gemm_grid, 256, 0, stream>>>(finB, Wt + 10 * WM, self_b, self_b,
                                             bufA, N, 1,
                                             nullptr, nullptr, nullptr, nullptr,
                                             sumsOf(8));
  k_classifier<<<nb8, 256, 0, stream>>>(bufA, cls_W, sumsOf(8), cls_b, out, N, 4 * D, 0);
}